// Round 1
// baseline (281.534 us; speedup 1.0000x reference)
//
#include <hip/hip_runtime.h>
#include <hip/hip_bf16.h>
#include <math.h>

#define PI_F 3.14159265358979f

typedef __attribute__((ext_vector_type(8))) short bf16x8;   // 8 bf16 (4 VGPRs)
typedef __attribute__((ext_vector_type(4))) float f32x4;

#define DM 512
#define LSEQ 2048
#define NB 8
#define NFFT 4096
#define MTOK (NB*LSEQ)

// ---------------- FFT: Stockham radix-2 in LDS, ping-pong ----------------
// Twiddle: folded half table with pad. Entry f in [0,1024): angle -2pi f/4096,
// stored at f + (f>>5). For t in [1024,2048): exp(-2pi i t/4096) = (s', -c').
#define TWSZ (1024 + 32)

__device__ __forceinline__ void tw_load(const float* twre, const float* twim,
                                        int t, float& wr, float& wi) {
  if (t < 1024) {
    int i = t + (t >> 5);
    wr = twre[i]; wi = twim[i];
  } else {
    int t2 = t - 1024;
    int i = t2 + (t2 >> 5);
    wr = twim[i]; wi = -twre[i];
  }
}

__device__ void build_tw(float* twre, float* twim, int tid, int nt) {
  for (int f = tid; f < 1024; f += nt) {
    float sv, cv;
    sincosf(-2.0f * PI_F * (float)f / 4096.0f, &sv, &cv);
    int i = f + (f >> 5);
    twre[i] = cv; twim[i] = sv;
  }
}

// Returns 0 if result is in (ar,ai), 1 if in (br,bi).
__device__ int fft_lds(float* ar, float* ai, float* br, float* bi,
                       const float* twre, const float* twim,
                       int N, int tid, int nt, int inverse) {
  float *sr = ar, *si = ai, *dr = br, *di = bi;
  int cur = 0;
  int half = N >> 1;
  for (int s = 0; (1 << s) < N; ++s) {
    int Ns = 1 << s;
    __syncthreads();
    for (int j = tid; j < half; j += nt) {
      int r = j & (Ns - 1);
      int q = j >> s;
      float xr = sr[j],        xi = si[j];
      float yr = sr[j + half], yi = si[j + half];
      int t = r * (NFFT >> (s + 1));
      float wr, wi;
      tw_load(twre, twim, t, wr, wi);
      if (inverse) wi = -wi;
      float tr = yr * wr - yi * wi;
      float ti = yr * wi + yi * wr;
      int idx = (q << (s + 1)) + r;
      dr[idx]      = xr + tr;  di[idx]      = xi + ti;
      dr[idx + Ns] = xr - tr;  di[idx + Ns] = xi - ti;
    }
    float* tp;
    tp = sr; sr = dr; dr = tp;
    tp = si; si = di; di = tp;
    cur ^= 1;
  }
  __syncthreads();
  return cur;
}

// ---------------- Kernel 1: S4 kernel generation ----------------
// One workgroup per channel h: Cauchy sums -> at_roots -> ifft(2048) -> K
// -> fft(4096) -> Kf[h][0..4095] (full complex spectrum).
__global__ __launch_bounds__(512) void k_gen(
    const float* __restrict__ lam_re, const float* __restrict__ lam_im,
    const float* __restrict__ p_re,   const float* __restrict__ p_im,
    const float* __restrict__ B_re,   const float* __restrict__ B_im,
    const float* __restrict__ Ct_re,  const float* __restrict__ Ct_im,
    const float* __restrict__ log_step, float2* __restrict__ Kf) {
  __shared__ float r0[NFFT], i0[NFFT], r1[NFFT], i1[NFFT];
  __shared__ float twre[TWSZ], twim[TWSZ];
  __shared__ float w00r[64], w00i[64], w01r[64], w01i[64],
                   w10r[64], w10i[64], w11[64], lre[64], lim[64];
  int h = blockIdx.x, tid = threadIdx.x;
  build_tw(twre, twim, tid, 512);
  if (tid < 64) {
    int n = tid;
    float br = B_re[h*64+n],  bi = B_im[h*64+n];
    float cr = Ct_re[h*64+n], ci = Ct_im[h*64+n];
    float pr = p_re[n],       pi = p_im[n];
    // a0 = conj(Ct), a1 = conj(p), b0 = B, b1 = p
    w00r[n] = cr*br + ci*bi;  w00i[n] = cr*bi - ci*br;
    w01r[n] = cr*pr + ci*pi;  w01i[n] = cr*pi - ci*pr;
    w10r[n] = pr*br + pi*bi;  w10i[n] = pr*bi - pi*br;
    w11[n]  = pr*pr + pi*pi;
    lre[n] = lam_re[n]; lim[n] = lam_im[n];
  }
  __syncthreads();
  float two_over_step = 2.0f * expf(-log_step[h]);
  for (int l = tid; l < LSEQ; l += 512) {
    float omi, omr;
    sincosf(-2.0f * PI_F * (float)l / (float)LSEQ, &omi, &omr);
    float a = 1.0f + omr;                 // 1+omega = (a, omi)
    float den = a*a + omi*omi;
    float invden = 1.0f / den;
    float cr = 2.0f * a * invden, ci = -2.0f * omi * invden;   // c = 2/(1+w)
    // (1-w)/(1+w) = ((1-|w|^2) - 2i*Im(w)) / |1+w|^2
    float gr = two_over_step * (1.0f - omr*omr - omi*omi) * invden;
    float gi = two_over_step * (-2.0f * omi) * invden;
    float k00r=0,k00i=0,k01r=0,k01i=0,k10r=0,k10i=0,k11r=0,k11i=0;
    #pragma unroll 8
    for (int n = 0; n < 64; ++n) {
      float dr = gr - lre[n], di = gi - lim[n];
      float inv = 1.0f / (dr*dr + di*di);
      float car = dr * inv, cai = -di * inv;     // 1/(g-lam)
      k00r += w00r[n]*car - w00i[n]*cai;  k00i += w00r[n]*cai + w00i[n]*car;
      k01r += w01r[n]*car - w01i[n]*cai;  k01i += w01r[n]*cai + w01i[n]*car;
      k10r += w10r[n]*car - w10i[n]*cai;  k10i += w10r[n]*cai + w10i[n]*car;
      k11r += w11[n]*car;                 k11i += w11[n]*cai;
    }
    // t = k01*k10/(1+k11)
    float tr = k01r*k10r - k01i*k10i, ti = k01r*k10i + k01i*k10r;
    float d1r = 1.0f + k11r, d1i = k11i;
    float invd1 = 1.0f / (d1r*d1r + d1i*d1i);
    float t2r = (tr*d1r + ti*d1i) * invd1;
    float t2i = (ti*d1r - tr*d1i) * invd1;
    float numr = k00r - t2r, numi = k00i - t2i;
    r0[l] = cr*numr - ci*numi;
    i0[l] = cr*numi + ci*numr;
  }
  // ifft(2048): K[m] = Re((1/L) * sum at_roots * e^{+2pi i l m / L})
  int res = fft_lds(r0, i0, r1, i1, twre, twim, LSEQ, tid, 512, 1);
  float* kr = res ? r1 : r0;
  for (int m = tid; m < NFFT; m += 512) {
    float v = (m < LSEQ) ? kr[m] * (1.0f / (float)LSEQ) : 0.0f;
    r0[m] = v;
    i0[m] = 0.0f;
  }
  // fft(4096) of real K -> full spectrum
  res = fft_lds(r0, i0, r1, i1, twre, twim, NFFT, tid, 512, 0);
  float* fr = res ? r1 : r0;
  float* fi = res ? i1 : i0;
  float2* ko = Kf + (size_t)h * NFFT;
  for (int f = tid; f < NFFT; f += 512)
    ko[f] = make_float2(fr[f], fi[f]);
}

// ---------------- Kernel 2: transpose u (B,L,D) -> ut (B,D,L) ----------------
__global__ __launch_bounds__(256) void k_tr_u(const float* __restrict__ u,
                                              float* __restrict__ ut) {
  __shared__ float t[32][33];
  int b = blockIdx.z;
  int l0 = blockIdx.x * 32, h0 = blockIdx.y * 32;
  int x = threadIdx.x, y0 = threadIdx.y;
  #pragma unroll
  for (int i = 0; i < 4; ++i) {
    int y = y0 + i*8;
    t[y][x] = u[((size_t)b*LSEQ + l0 + y) * DM + h0 + x];
  }
  __syncthreads();
  #pragma unroll
  for (int i = 0; i < 4; ++i) {
    int y = y0 + i*8;
    ut[((size_t)b*DM + h0 + y) * LSEQ + l0 + x] = t[x][y];
  }
}

// ---------------- Kernel 3: FFT convolution + D*u + GELU (in-place on ut) ---
// One workgroup per (batch, channel-pair). Two real channels packed into one
// complex FFT: Z = FFT(u0 + i*u1); U0 = (Z + conj(Zrev))/2, U1 = -i(Z - conj(Zrev))/2;
// Y = U0*K0 + i*(U1*K1); ifft(Y) = y0 + i*y1 (both real).
__global__ __launch_bounds__(512) void k_conv(float* __restrict__ ut,
                                              const float2* __restrict__ Kf,
                                              const float* __restrict__ Dvec) {
  __shared__ float r0[NFFT], i0[NFFT], r1[NFFT], i1[NFFT];
  __shared__ float twre[TWSZ], twim[TWSZ];
  int wg = blockIdx.x;
  int b = wg >> 8, hp = wg & 255;
  int h0 = hp * 2, h1 = h0 + 1;
  int tid = threadIdx.x;
  build_tw(twre, twim, tid, 512);
  float* u0p = ut + ((size_t)(b*DM + h0)) * LSEQ;
  float* u1p = ut + ((size_t)(b*DM + h1)) * LSEQ;
  float u0reg[4], u1reg[4];
  #pragma unroll
  for (int i = 0; i < 4; ++i) {
    int l = tid + i*512;
    float a = u0p[l], c = u1p[l];
    u0reg[i] = a; u1reg[i] = c;
    r0[l] = a;  i0[l] = c;
    r0[l + LSEQ] = 0.0f;  i0[l + LSEQ] = 0.0f;
  }
  int res = fft_lds(r0, i0, r1, i1, twre, twim, NFFT, tid, 512, 0);  // -> 0
  float* Zr = res ? r1 : r0;  float* Zi = res ? i1 : i0;
  float* Yr = res ? r0 : r1;  float* Yi = res ? i0 : i1;
  const float2* k0p = Kf + (size_t)h0 * NFFT;
  const float2* k1p = Kf + (size_t)h1 * NFFT;
  for (int f = tid; f < NFFT; f += 512) {
    int fn = (NFFT - f) & (NFFT - 1);
    float ar = Zr[f],  ai = Zi[f];
    float br = Zr[fn], bi = -Zi[fn];
    float u0r = 0.5f*(ar + br), u0i = 0.5f*(ai + bi);
    float u1r = 0.5f*(ai - bi), u1i = -0.5f*(ar - br);
    float2 K0 = k0p[f], K1 = k1p[f];
    float y0r = u0r*K0.x - u0i*K0.y, y0i = u0r*K0.y + u0i*K0.x;
    float y1r = u1r*K1.x - u1i*K1.y, y1i = u1r*K1.y + u1i*K1.x;
    Yr[f] = y0r - y1i;
    Yi[f] = y0i + y1r;
  }
  int res2 = fft_lds(Yr, Yi, Zr, Zi, twre, twim, NFFT, tid, 512, 1);  // -> 0
  float* rr = res2 ? Zr : Yr;
  float* ri = res2 ? Zi : Yi;
  float d0 = Dvec[h0], d1 = Dvec[h1];
  const float inv_n = 1.0f / (float)NFFT;
  #pragma unroll
  for (int i = 0; i < 4; ++i) {
    int l = tid + i*512;
    float y0 = rr[l]*inv_n + d0*u0reg[i];
    float y1 = ri[l]*inv_n + d1*u1reg[i];
    u0p[l] = 0.5f*y0*(1.0f + erff(y0*0.70710678118f));
    u1p[l] = 0.5f*y1*(1.0f + erff(y1*0.70710678118f));
  }
}

// ---------------- Kernel 4: transpose z (B,D,L) f32 -> Zb (M,D) bf16 --------
__global__ __launch_bounds__(256) void k_tr_z(const float* __restrict__ zt,
                                              __hip_bfloat16* __restrict__ Zb) {
  __shared__ float t[32][33];
  int b = blockIdx.z;
  int h0 = blockIdx.x * 32, l0 = blockIdx.y * 32;
  int x = threadIdx.x, y0 = threadIdx.y;
  #pragma unroll
  for (int i = 0; i < 4; ++i) {
    int y = y0 + i*8;
    t[y][x] = zt[((size_t)b*DM + h0 + y) * LSEQ + l0 + x];
  }
  __syncthreads();
  #pragma unroll
  for (int i = 0; i < 4; ++i) {
    int y = y0 + i*8;
    Zb[((size_t)b*LSEQ + l0 + y) * DM + h0 + x] = __float2bfloat16(t[x][y]);
  }
}

// ---------------- Kernel 5: cast W to bf16 ----------------
__global__ __launch_bounds__(256) void k_cast_w(const float* __restrict__ W,
                                                __hip_bfloat16* __restrict__ Wb) {
  int i = blockIdx.x * 256 + threadIdx.x;
  Wb[i] = __float2bfloat16(W[i]);
}

// ---------------- Kernel 6: GEMM  out = Z @ W^T + b + u  (pre-LN) ----------
// C[m][o] = sum_h Z[m][h] * W[o][h];  64x64 tile, 4 waves, mfma 16x16x32 bf16.
__global__ __launch_bounds__(256) void k_gemm(const short* __restrict__ Z,
                                              const short* __restrict__ Wb,
                                              const float* __restrict__ bias,
                                              const float* __restrict__ u,
                                              float* __restrict__ gout) {
  __shared__ short sA[64][40];   // +8 pad to dodge bank conflicts
  __shared__ short sB[64][40];
  int tid = threadIdx.x;
  int wave = tid >> 6, lane = tid & 63;
  int wm = wave >> 1, wn = wave & 1;
  int m0 = blockIdx.x * 64, n0 = blockIdx.y * 64;
  int srow = tid >> 2, skb = (tid & 3) << 3;   // staging: 16B per thread
  int row = lane & 15, kq8 = (lane >> 4) << 3;
  f32x4 acc00 = {0.f,0.f,0.f,0.f}, acc01 = {0.f,0.f,0.f,0.f};
  f32x4 acc10 = {0.f,0.f,0.f,0.f}, acc11 = {0.f,0.f,0.f,0.f};
  for (int k0 = 0; k0 < DM; k0 += 32) {
    __syncthreads();
    *(uint4*)&sA[srow][skb] = *(const uint4*)(Z  + (size_t)(m0 + srow) * DM + k0 + skb);
    *(uint4*)&sB[srow][skb] = *(const uint4*)(Wb + (size_t)(n0 + srow) * DM + k0 + skb);
    __syncthreads();
    bf16x8 a0 = *(const bf16x8*)&sA[wm*32 + row][kq8];
    bf16x8 a1 = *(const bf16x8*)&sA[wm*32 + 16 + row][kq8];
    bf16x8 b0 = *(const bf16x8*)&sB[wn*32 + row][kq8];
    bf16x8 b1 = *(const bf16x8*)&sB[wn*32 + 16 + row][kq8];
    acc00 = __builtin_amdgcn_mfma_f32_16x16x32_bf16(a0, b0, acc00, 0, 0, 0);
    acc01 = __builtin_amdgcn_mfma_f32_16x16x32_bf16(a0, b1, acc01, 0, 0, 0);
    acc10 = __builtin_amdgcn_mfma_f32_16x16x32_bf16(a1, b0, acc10, 0, 0, 0);
    acc11 = __builtin_amdgcn_mfma_f32_16x16x32_bf16(a1, b1, acc11, 0, 0, 0);
  }
  int crow = (lane >> 4) << 2, ccol = lane & 15;
  #pragma unroll
  for (int rr = 0; rr < 4; ++rr) {
    int mmA = m0 + wm*32 + crow + rr;
    int mmB = mmA + 16;
    int ooA = n0 + wn*32 + ccol;
    int ooB = ooA + 16;
    size_t iAA = (size_t)mmA * DM + ooA, iAB = (size_t)mmA * DM + ooB;
    size_t iBA = (size_t)mmB * DM + ooA, iBB = (size_t)mmB * DM + ooB;
    gout[iAA] = acc00[rr] + bias[ooA] + u[iAA];
    gout[iAB] = acc01[rr] + bias[ooB] + u[iAB];
    gout[iBA] = acc10[rr] + bias[ooA] + u[iBA];
    gout[iBB] = acc11[rr] + bias[ooB] + u[iBB];
  }
}

// ---------------- Kernel 7: LayerNorm ----------------
__global__ __launch_bounds__(512) void k_ln(const float* __restrict__ pre,
                                            const float* __restrict__ lnw,
                                            const float* __restrict__ lnb,
                                            float* __restrict__ out) {
  int wave = threadIdx.x >> 6, lane = threadIdx.x & 63;
  int m = blockIdx.x * 8 + wave;
  const float* row = pre + (size_t)m * DM;
  float v[8]; float s = 0.f, s2 = 0.f;
  #pragma unroll
  for (int i = 0; i < 8; ++i) {
    v[i] = row[lane + i*64];
    s += v[i]; s2 += v[i]*v[i];
  }
  #pragma unroll
  for (int off = 1; off < 64; off <<= 1) {
    s  += __shfl_xor(s, off);
    s2 += __shfl_xor(s2, off);
  }
  float mean = s * (1.0f/(float)DM);
  float var  = s2 * (1.0f/(float)DM) - mean*mean;
  float rstd = rsqrtf(var + 1e-5f);
  float* orow = out + (size_t)m * DM;
  #pragma unroll
  for (int i = 0; i < 8; ++i) {
    int o = lane + i*64;
    orow[o] = (v[i] - mean) * rstd * lnw[o] + lnb[o];
  }
}

// ---------------- launch ----------------
extern "C" void kernel_launch(void* const* d_in, const int* in_sizes, int n_in,
                              void* d_out, int out_size, void* d_ws, size_t ws_size,
                              hipStream_t stream) {
  const float* u        = (const float*)d_in[0];
  const float* lam_re   = (const float*)d_in[1];
  const float* lam_im   = (const float*)d_in[2];
  const float* p_re     = (const float*)d_in[3];
  const float* p_im     = (const float*)d_in[4];
  const float* B_re     = (const float*)d_in[5];
  const float* B_im     = (const float*)d_in[6];
  const float* Ct_re    = (const float*)d_in[7];
  const float* Ct_im    = (const float*)d_in[8];
  const float* log_step = (const float*)d_in[9];
  const float* Dv       = (const float*)d_in[10];
  const float* W        = (const float*)d_in[11];
  const float* bias     = (const float*)d_in[12];
  const float* ln_w     = (const float*)d_in[13];
  const float* ln_b     = (const float*)d_in[14];
  float* out = (float*)d_out;
  char* ws = (char*)d_ws;

  // ws layout: Kf (16 MB) | ut/z/gemm-out (32 MB) | Zb bf16 (16 MB) | Wb (0.5 MB)
  float2* Kf = (float2*)ws;
  float*  ut = (float*)(ws + (16u << 20));
  __hip_bfloat16* Zb = (__hip_bfloat16*)(ws + (48u << 20));
  __hip_bfloat16* Wb = (__hip_bfloat16*)(ws + (64u << 20));
  float* gout = ut;   // reuse after Zb is produced
  if (ws_size < (65u << 20)) return;

  k_gen<<<dim3(DM), dim3(512), 0, stream>>>(lam_re, lam_im, p_re, p_im,
                                            B_re, B_im, Ct_re, Ct_im, log_step, Kf);
  k_tr_u<<<dim3(LSEQ/32, DM/32, NB), dim3(32, 8), 0, stream>>>(u, ut);
  k_conv<<<dim3(NB * (DM/2)), dim3(512), 0, stream>>>(ut, Kf, Dv);
  k_tr_z<<<dim3(DM/32, LSEQ/32, NB), dim3(32, 8), 0, stream>>>(ut, Zb);
  k_cast_w<<<dim3((DM*DM)/256), dim3(256), 0, stream>>>(W, Wb);
  k_gemm<<<dim3(MTOK/64, DM/64), dim3(256), 0, stream>>>((const short*)Zb, (const short*)Wb,
                                                         bias, u, gout);
  k_ln<<<dim3(MTOK/8), dim3(512), 0, stream>>>(gout, ln_w, ln_b, out);
}

// Round 2
// 199.128 us; speedup vs baseline: 1.4138x; 1.4138x over previous
//
#include <hip/hip_runtime.h>
#include <hip/hip_bf16.h>
#include <math.h>

#define PI_F 3.14159265358979f

typedef __attribute__((ext_vector_type(8))) short bf16x8;   // 8 bf16 (4 VGPRs)
typedef __attribute__((ext_vector_type(4))) float f32x4;

#define DM 512
#define LSEQ 2048
#define NB 8
#define NFFT 4096
#define MTOK (NB*LSEQ)

// Padded LDS index: +1 word per 32 -> stride-512 reads stay 2-way (free).
__device__ __forceinline__ int PD(int i) { return i + (i >> 5); }
#define LDSN 4224   // PD(4095)=4222

// ---------------- 8-point DFT in registers ----------------
template<bool INV>
__device__ __forceinline__ void dft8(const float xr[8], const float xi[8],
                                     float yr[8], float yi[8]) {
  const float C = 0.70710678118654752f;
  float t0r=xr[0]+xr[4], t0i=xi[0]+xi[4];
  float t1r=xr[0]-xr[4], t1i=xi[0]-xi[4];
  float t2r=xr[2]+xr[6], t2i=xi[2]+xi[6];
  float t3r=xr[2]-xr[6], t3i=xi[2]-xi[6];
  float it3r = INV ? -t3i : t3i;
  float it3i = INV ?  t3r : -t3r;
  float E0r=t0r+t2r, E0i=t0i+t2i;
  float E2r=t0r-t2r, E2i=t0i-t2i;
  float E1r=t1r+it3r, E1i=t1i+it3i;
  float E3r=t1r-it3r, E3i=t1i-it3i;
  float u0r=xr[1]+xr[5], u0i=xi[1]+xi[5];
  float u1r=xr[1]-xr[5], u1i=xi[1]-xi[5];
  float u2r=xr[3]+xr[7], u2i=xi[3]+xi[7];
  float u3r=xr[3]-xr[7], u3i=xi[3]-xi[7];
  float iu3r = INV ? -u3i : u3i;
  float iu3i = INV ?  u3r : -u3r;
  float O0r=u0r+u2r, O0i=u0i+u2i;
  float O2r=u0r-u2r, O2i=u0i-u2i;
  float O1r=u1r+iu3r, O1i=u1i+iu3i;
  float O3r=u1r-iu3r, O3i=u1i-iu3i;
  float w1r = INV ? C*(O1r-O1i) : C*(O1r+O1i);
  float w1i = INV ? C*(O1r+O1i) : C*(O1i-O1r);
  float w2r = INV ? -O2i : O2i;
  float w2i = INV ?  O2r : -O2r;
  float w3r = INV ? -C*(O3r+O3i) : C*(O3i-O3r);
  float w3i = INV ?  C*(O3r-O3i) : -C*(O3r+O3i);
  yr[0]=E0r+O0r; yi[0]=E0i+O0i;
  yr[4]=E0r-O0r; yi[4]=E0i-O0i;
  yr[1]=E1r+w1r; yi[1]=E1i+w1i;
  yr[5]=E1r-w1r; yi[5]=E1i-w1i;
  yr[2]=E2r+w2r; yi[2]=E2i+w2i;
  yr[6]=E2r-w2r; yi[6]=E2i-w2i;
  yr[3]=E3r+w3r; yi[3]=E3i+w3i;
  yr[7]=E3r-w3r; yi[7]=E3i-w3i;
}

// ---------------- Stockham radix-8 stage (register-staged, single buffer) ---
// Ns = 1<<SH already combined; NBF butterflies; twiddle base w1 = (c1, +-s1f).
template<bool INV, int SH, int NBF>
__device__ __forceinline__ void r8_stage(float* sr, float* si, int tid,
                                         float c1, float s1f) {
  float yr[8], yi[8];
  bool act = (NBF >= 512) || (tid < NBF);
  __syncthreads();
  if (act) {
    float xr[8], xi[8];
    #pragma unroll
    for (int m = 0; m < 8; ++m) {
      int ix = PD(tid + m * NBF);
      xr[m] = sr[ix]; xi[m] = si[ix];
    }
    if (SH > 0) {
      float s1 = INV ? -s1f : s1f;
      float wr = c1, wi = s1;
      #pragma unroll
      for (int m = 1; m < 8; ++m) {
        float tr = xr[m]*wr - xi[m]*wi;
        float ti = xr[m]*wi + xi[m]*wr;
        xr[m] = tr; xi[m] = ti;
        float nr = wr*c1 - wi*s1;
        float ni = wr*s1 + wi*c1;
        wr = nr; wi = ni;
      }
    }
    dft8<INV>(xr, xi, yr, yi);
  }
  __syncthreads();
  if (act) {
    int r = tid & ((1 << SH) - 1);
    int q = tid >> SH;
    int base = (q << (SH + 3)) + r;
    #pragma unroll
    for (int p = 0; p < 8; ++p) {
      int ix = PD(base + p * (1 << SH));
      sr[ix] = yr[p]; si[ix] = yi[p];
    }
  }
}

// ---------------- Stockham radix-4 stage (final stage for N=2048) ----------
template<bool INV, int SH, int NBF>
__device__ __forceinline__ void r4_stage(float* sr, float* si, int tid,
                                         float c1, float s1f) {
  float yr[4], yi[4];
  bool act = (NBF >= 512) || (tid < NBF);
  __syncthreads();
  if (act) {
    float xr[4], xi[4];
    #pragma unroll
    for (int m = 0; m < 4; ++m) {
      int ix = PD(tid + m * NBF);
      xr[m] = sr[ix]; xi[m] = si[ix];
    }
    if (SH > 0) {
      float s1 = INV ? -s1f : s1f;
      float wr = c1, wi = s1;
      #pragma unroll
      for (int m = 1; m < 4; ++m) {
        float tr = xr[m]*wr - xi[m]*wi;
        float ti = xr[m]*wi + xi[m]*wr;
        xr[m] = tr; xi[m] = ti;
        float nr = wr*c1 - wi*s1;
        float ni = wr*s1 + wi*c1;
        wr = nr; wi = ni;
      }
    }
    float t0r=xr[0]+xr[2], t0i=xi[0]+xi[2];
    float t1r=xr[0]-xr[2], t1i=xi[0]-xi[2];
    float t2r=xr[1]+xr[3], t2i=xi[1]+xi[3];
    float t3r=xr[1]-xr[3], t3i=xi[1]-xi[3];
    float it3r = INV ? -t3i : t3i;
    float it3i = INV ?  t3r : -t3r;
    yr[0]=t0r+t2r; yi[0]=t0i+t2i;
    yr[2]=t0r-t2r; yi[2]=t0i-t2i;
    yr[1]=t1r+it3r; yi[1]=t1i+it3i;
    yr[3]=t1r-it3r; yi[3]=t1i-it3i;
  }
  __syncthreads();
  if (act) {
    int r = tid & ((1 << SH) - 1);
    int q = tid >> SH;
    int base = (q << (SH + 2)) + r;
    #pragma unroll
    for (int p = 0; p < 4; ++p) {
      int ix = PD(base + p * (1 << SH));
      sr[ix] = yr[p]; si[ix] = yi[p];
    }
  }
}

// 4096 = 8*8*8*8
template<bool INV>
__device__ __forceinline__ void fft4096(float* sr, float* si, int tid,
                                        float c3, float s3, float c6, float s6,
                                        float c9, float s9) {
  r8_stage<INV, 0, 512>(sr, si, tid, 1.f, 0.f);
  r8_stage<INV, 3, 512>(sr, si, tid, c3, s3);
  r8_stage<INV, 6, 512>(sr, si, tid, c6, s6);
  r8_stage<INV, 9, 512>(sr, si, tid, c9, s9);
  __syncthreads();
}

// 2048 = 8*8*8*4
template<bool INV>
__device__ __forceinline__ void fft2048(float* sr, float* si, int tid,
                                        float c3, float s3, float c6, float s6,
                                        float c9, float s9) {
  r8_stage<INV, 0, 256>(sr, si, tid, 1.f, 0.f);
  r8_stage<INV, 3, 256>(sr, si, tid, c3, s3);
  r8_stage<INV, 6, 256>(sr, si, tid, c6, s6);
  r4_stage<INV, 9, 512>(sr, si, tid, c9, s9);
  __syncthreads();
}

// ---------------- Kernel 1: S4 kernel generation ----------------
__global__ __launch_bounds__(512) void k_gen(
    const float* __restrict__ lam_re, const float* __restrict__ lam_im,
    const float* __restrict__ p_re,   const float* __restrict__ p_im,
    const float* __restrict__ B_re,   const float* __restrict__ B_im,
    const float* __restrict__ Ct_re,  const float* __restrict__ Ct_im,
    const float* __restrict__ log_step, float2* __restrict__ Kf) {
  __shared__ float sr[LDSN], si[LDSN];
  __shared__ float w00r[64], w00i[64], w01r[64], w01i[64],
                   w10r[64], w10i[64], w11[64], lre[64], lim[64];
  int h = blockIdx.x, tid = threadIdx.x;
  // per-thread stage twiddle bases
  float c3, s3, c6, s6, c9a, s9a, c9b, s9b;
  { int r = tid & 7;   sincosf(-2.f*PI_F*(float)r/64.f,   &s3,  &c3);  }
  { int r = tid & 63;  sincosf(-2.f*PI_F*(float)r/512.f,  &s6,  &c6);  }
  { int r = tid & 511; sincosf(-2.f*PI_F*(float)r/4096.f, &s9a, &c9a); }
  { int r = tid & 511; sincosf(-2.f*PI_F*(float)r/2048.f, &s9b, &c9b); }
  if (tid < 64) {
    int n = tid;
    float br = B_re[h*64+n],  bi = B_im[h*64+n];
    float cr = Ct_re[h*64+n], ci = Ct_im[h*64+n];
    float pr = p_re[n],       pi = p_im[n];
    w00r[n] = cr*br + ci*bi;  w00i[n] = cr*bi - ci*br;
    w01r[n] = cr*pr + ci*pi;  w01i[n] = cr*pi - ci*pr;
    w10r[n] = pr*br + pi*bi;  w10i[n] = pr*bi - pi*br;
    w11[n]  = pr*pr + pi*pi;
    lre[n] = lam_re[n]; lim[n] = lam_im[n];
  }
  __syncthreads();
  float two_over_step = 2.0f * expf(-log_step[h]);
  for (int l = tid; l < LSEQ; l += 512) {
    float omi, omr;
    sincosf(-2.0f * PI_F * (float)l / (float)LSEQ, &omi, &omr);
    float a = 1.0f + omr;
    float invden = 1.0f / (a*a + omi*omi);
    float cr = 2.0f * a * invden, ci = -2.0f * omi * invden;
    float gr = two_over_step * (1.0f - omr*omr - omi*omi) * invden;
    float gi = two_over_step * (-2.0f * omi) * invden;
    float k00r=0,k00i=0,k01r=0,k01i=0,k10r=0,k10i=0,k11r=0,k11i=0;
    #pragma unroll 8
    for (int n = 0; n < 64; ++n) {
      float dr = gr - lre[n], di = gi - lim[n];
      float inv = 1.0f / (dr*dr + di*di);
      float car = dr * inv, cai = -di * inv;
      k00r += w00r[n]*car - w00i[n]*cai;  k00i += w00r[n]*cai + w00i[n]*car;
      k01r += w01r[n]*car - w01i[n]*cai;  k01i += w01r[n]*cai + w01i[n]*car;
      k10r += w10r[n]*car - w10i[n]*cai;  k10i += w10r[n]*cai + w10i[n]*car;
      k11r += w11[n]*car;                 k11i += w11[n]*cai;
    }
    float tr = k01r*k10r - k01i*k10i, ti = k01r*k10i + k01i*k10r;
    float d1r = 1.0f + k11r, d1i = k11i;
    float invd1 = 1.0f / (d1r*d1r + d1i*d1i);
    float t2r = (tr*d1r + ti*d1i) * invd1;
    float t2i = (ti*d1r - tr*d1i) * invd1;
    float numr = k00r - t2r, numi = k00i - t2i;
    sr[PD(l)] = cr*numr - ci*numi;
    si[PD(l)] = cr*numi + ci*numr;
  }
  // ifft2048 (unscaled conj transform), scale, realify, zero-pad to 4096
  fft2048<true>(sr, si, tid, c3, s3, c6, s6, c9b, s9b);
  for (int m = tid; m < NFFT; m += 512) {
    float v = (m < LSEQ) ? sr[PD(m)] * (1.0f / (float)LSEQ) : 0.0f;
    sr[PD(m)] = v;
    si[PD(m)] = 0.0f;
  }
  fft4096<false>(sr, si, tid, c3, s3, c6, s6, c9a, s9a);
  float2* ko = Kf + (size_t)h * NFFT;
  for (int f = tid; f < NFFT; f += 512)
    ko[f] = make_float2(sr[PD(f)], si[PD(f)]);
}

// ---------------- Kernel 2: transpose u (B,L,D) -> ut (B,D,L) ----------------
__global__ __launch_bounds__(256) void k_tr_u(const float* __restrict__ u,
                                              float* __restrict__ ut) {
  __shared__ float t[32][33];
  int b = blockIdx.z;
  int l0 = blockIdx.x * 32, h0 = blockIdx.y * 32;
  int x = threadIdx.x, y0 = threadIdx.y;
  #pragma unroll
  for (int i = 0; i < 4; ++i) {
    int y = y0 + i*8;
    t[y][x] = u[((size_t)b*LSEQ + l0 + y) * DM + h0 + x];
  }
  __syncthreads();
  #pragma unroll
  for (int i = 0; i < 4; ++i) {
    int y = y0 + i*8;
    ut[((size_t)b*DM + h0 + y) * LSEQ + l0 + x] = t[x][y];
  }
}

// ---------------- Kernel 3: FFT convolution + D*u + GELU (in-place) --------
__global__ __launch_bounds__(512) void k_conv(float* __restrict__ ut,
                                              const float2* __restrict__ Kf,
                                              const float* __restrict__ Dvec) {
  __shared__ float sr[LDSN], si[LDSN];
  int wg = blockIdx.x;
  int b = wg >> 8, hp = wg & 255;
  int h0 = hp * 2, h1 = h0 + 1;
  int tid = threadIdx.x;
  float c3, s3, c6, s6, c9, s9;
  { int r = tid & 7;   sincosf(-2.f*PI_F*(float)r/64.f,   &s3, &c3); }
  { int r = tid & 63;  sincosf(-2.f*PI_F*(float)r/512.f,  &s6, &c6); }
  { int r = tid & 511; sincosf(-2.f*PI_F*(float)r/4096.f, &s9, &c9); }
  float* u0p = ut + ((size_t)(b*DM + h0)) * LSEQ;
  float* u1p = ut + ((size_t)(b*DM + h1)) * LSEQ;
  float u0reg[4], u1reg[4];
  #pragma unroll
  for (int i = 0; i < 4; ++i) {
    int l = tid + i*512;
    float a = u0p[l], c = u1p[l];
    u0reg[i] = a; u1reg[i] = c;
    sr[PD(l)] = a;  si[PD(l)] = c;
    sr[PD(l + LSEQ)] = 0.0f;  si[PD(l + LSEQ)] = 0.0f;
  }
  fft4096<false>(sr, si, tid, c3, s3, c6, s6, c9, s9);
  // spectral: unpack 2 real channels, multiply by K0/K1, repack
  float yrg[8], yig[8];
  const float2* k0p = Kf + (size_t)h0 * NFFT;
  const float2* k1p = Kf + (size_t)h1 * NFFT;
  #pragma unroll
  for (int i = 0; i < 8; ++i) {
    int f = tid + i*512;
    int fn = (NFFT - f) & (NFFT - 1);
    float ar = sr[PD(f)],  ai = si[PD(f)];
    float br = sr[PD(fn)], bi = -si[PD(fn)];
    float u0r = 0.5f*(ar + br), u0i = 0.5f*(ai + bi);
    float u1r = 0.5f*(ai - bi), u1i = -0.5f*(ar - br);
    float2 K0 = k0p[f], K1 = k1p[f];
    float y0r = u0r*K0.x - u0i*K0.y, y0i = u0r*K0.y + u0i*K0.x;
    float y1r = u1r*K1.x - u1i*K1.y, y1i = u1r*K1.y + u1i*K1.x;
    yrg[i] = y0r - y1i;
    yig[i] = y0i + y1r;
  }
  __syncthreads();
  #pragma unroll
  for (int i = 0; i < 8; ++i) {
    int f = tid + i*512;
    sr[PD(f)] = yrg[i]; si[PD(f)] = yig[i];
  }
  fft4096<true>(sr, si, tid, c3, s3, c6, s6, c9, s9);
  float d0 = Dvec[h0], d1 = Dvec[h1];
  const float inv_n = 1.0f / (float)NFFT;
  #pragma unroll
  for (int i = 0; i < 4; ++i) {
    int l = tid + i*512;
    float y0 = sr[PD(l)]*inv_n + d0*u0reg[i];
    float y1 = si[PD(l)]*inv_n + d1*u1reg[i];
    u0p[l] = 0.5f*y0*(1.0f + erff(y0*0.70710678118f));
    u1p[l] = 0.5f*y1*(1.0f + erff(y1*0.70710678118f));
  }
}

// ---------------- Kernel 4: transpose z (B,D,L) f32 -> Zb (M,D) bf16 --------
__global__ __launch_bounds__(256) void k_tr_z(const float* __restrict__ zt,
                                              __hip_bfloat16* __restrict__ Zb) {
  __shared__ float t[32][33];
  int b = blockIdx.z;
  int h0 = blockIdx.x * 32, l0 = blockIdx.y * 32;
  int x = threadIdx.x, y0 = threadIdx.y;
  #pragma unroll
  for (int i = 0; i < 4; ++i) {
    int y = y0 + i*8;
    t[y][x] = zt[((size_t)b*DM + h0 + y) * LSEQ + l0 + x];
  }
  __syncthreads();
  #pragma unroll
  for (int i = 0; i < 4; ++i) {
    int y = y0 + i*8;
    Zb[((size_t)b*LSEQ + l0 + y) * DM + h0 + x] = __float2bfloat16(t[x][y]);
  }
}

// ---------------- Kernel 5: cast W to bf16 ----------------
__global__ __launch_bounds__(256) void k_cast_w(const float* __restrict__ W,
                                                __hip_bfloat16* __restrict__ Wb) {
  int i = blockIdx.x * 256 + threadIdx.x;
  Wb[i] = __float2bfloat16(W[i]);
}

// ---------------- Kernel 6: GEMM  out = Z @ W^T + b + u  (pre-LN) ----------
__global__ __launch_bounds__(256) void k_gemm(const short* __restrict__ Z,
                                              const short* __restrict__ Wb,
                                              const float* __restrict__ bias,
                                              const float* __restrict__ u,
                                              float* __restrict__ gout) {
  __shared__ short sA[64][40];
  __shared__ short sB[64][40];
  int tid = threadIdx.x;
  int wave = tid >> 6, lane = tid & 63;
  int wm = wave >> 1, wn = wave & 1;
  int m0 = blockIdx.x * 64, n0 = blockIdx.y * 64;
  int srow = tid >> 2, skb = (tid & 3) << 3;
  int row = lane & 15, kq8 = (lane >> 4) << 3;
  f32x4 acc00 = {0.f,0.f,0.f,0.f}, acc01 = {0.f,0.f,0.f,0.f};
  f32x4 acc10 = {0.f,0.f,0.f,0.f}, acc11 = {0.f,0.f,0.f,0.f};
  for (int k0 = 0; k0 < DM; k0 += 32) {
    __syncthreads();
    *(uint4*)&sA[srow][skb] = *(const uint4*)(Z  + (size_t)(m0 + srow) * DM + k0 + skb);
    *(uint4*)&sB[srow][skb] = *(const uint4*)(Wb + (size_t)(n0 + srow) * DM + k0 + skb);
    __syncthreads();
    bf16x8 a0 = *(const bf16x8*)&sA[wm*32 + row][kq8];
    bf16x8 a1 = *(const bf16x8*)&sA[wm*32 + 16 + row][kq8];
    bf16x8 b0 = *(const bf16x8*)&sB[wn*32 + row][kq8];
    bf16x8 b1 = *(const bf16x8*)&sB[wn*32 + 16 + row][kq8];
    acc00 = __builtin_amdgcn_mfma_f32_16x16x32_bf16(a0, b0, acc00, 0, 0, 0);
    acc01 = __builtin_amdgcn_mfma_f32_16x16x32_bf16(a0, b1, acc01, 0, 0, 0);
    acc10 = __builtin_amdgcn_mfma_f32_16x16x32_bf16(a1, b0, acc10, 0, 0, 0);
    acc11 = __builtin_amdgcn_mfma_f32_16x16x32_bf16(a1, b1, acc11, 0, 0, 0);
  }
  int crow = (lane >> 4) << 2, ccol = lane & 15;
  #pragma unroll
  for (int rr = 0; rr < 4; ++rr) {
    int mmA = m0 + wm*32 + crow + rr;
    int mmB = mmA + 16;
    int ooA = n0 + wn*32 + ccol;
    int ooB = ooA + 16;
    size_t iAA = (size_t)mmA * DM + ooA, iAB = (size_t)mmA * DM + ooB;
    size_t iBA = (size_t)mmB * DM + ooA, iBB = (size_t)mmB * DM + ooB;
    gout[iAA] = acc00[rr] + bias[ooA] + u[iAA];
    gout[iAB] = acc01[rr] + bias[ooB] + u[iAB];
    gout[iBA] = acc10[rr] + bias[ooA] + u[iBA];
    gout[iBB] = acc11[rr] + bias[ooB] + u[iBB];
  }
}

// ---------------- Kernel 7: LayerNorm ----------------
__global__ __launch_bounds__(512) void k_ln(const float* __restrict__ pre,
                                            const float* __restrict__ lnw,
                                            const float* __restrict__ lnb,
                                            float* __restrict__ out) {
  int wave = threadIdx.x >> 6, lane = threadIdx.x & 63;
  int m = blockIdx.x * 8 + wave;
  const float* row = pre + (size_t)m * DM;
  float v[8]; float s = 0.f, s2 = 0.f;
  #pragma unroll
  for (int i = 0; i < 8; ++i) {
    v[i] = row[lane + i*64];
    s += v[i]; s2 += v[i]*v[i];
  }
  #pragma unroll
  for (int off = 1; off < 64; off <<= 1) {
    s  += __shfl_xor(s, off);
    s2 += __shfl_xor(s2, off);
  }
  float mean = s * (1.0f/(float)DM);
  float var  = s2 * (1.0f/(float)DM) - mean*mean;
  float rstd = rsqrtf(var + 1e-5f);
  float* orow = out + (size_t)m * DM;
  #pragma unroll
  for (int i = 0; i < 8; ++i) {
    int o = lane + i*64;
    orow[o] = (v[i] - mean) * rstd * lnw[o] + lnb[o];
  }
}

// ---------------- launch ----------------
extern "C" void kernel_launch(void* const* d_in, const int* in_sizes, int n_in,
                              void* d_out, int out_size, void* d_ws, size_t ws_size,
                              hipStream_t stream) {
  const float* u        = (const float*)d_in[0];
  const float* lam_re   = (const float*)d_in[1];
  const float* lam_im   = (const float*)d_in[2];
  const float* p_re     = (const float*)d_in[3];
  const float* p_im     = (const float*)d_in[4];
  const float* B_re     = (const float*)d_in[5];
  const float* B_im     = (const float*)d_in[6];
  const float* Ct_re    = (const float*)d_in[7];
  const float* Ct_im    = (const float*)d_in[8];
  const float* log_step = (const float*)d_in[9];
  const float* Dv       = (const float*)d_in[10];
  const float* W        = (const float*)d_in[11];
  const float* bias     = (const float*)d_in[12];
  const float* ln_w     = (const float*)d_in[13];
  const float* ln_b     = (const float*)d_in[14];
  float* out = (float*)d_out;
  char* ws = (char*)d_ws;

  float2* Kf = (float2*)ws;
  float*  ut = (float*)(ws + (16u << 20));
  __hip_bfloat16* Zb = (__hip_bfloat16*)(ws + (48u << 20));
  __hip_bfloat16* Wb = (__hip_bfloat16*)(ws + (64u << 20));
  float* gout = ut;
  if (ws_size < (65u << 20)) return;

  k_gen<<<dim3(DM), dim3(512), 0, stream>>>(lam_re, lam_im, p_re, p_im,
                                            B_re, B_im, Ct_re, Ct_im, log_step, Kf);
  k_tr_u<<<dim3(LSEQ/32, DM/32, NB), dim3(32, 8), 0, stream>>>(u, ut);
  k_conv<<<dim3(NB * (DM/2)), dim3(512), 0, stream>>>(ut, Kf, Dv);
  k_tr_z<<<dim3(DM/32, LSEQ/32, NB), dim3(32, 8), 0, stream>>>(ut, Zb);
  k_cast_w<<<dim3((DM*DM)/256), dim3(256), 0, stream>>>(W, Wb);
  k_gemm<<<dim3(MTOK/64, DM/64), dim3(256), 0, stream>>>((const short*)Zb, (const short*)Wb,
                                                         bias, u, gout);
  k_ln<<<dim3(MTOK/8), dim3(512), 0, stream>>>(gout, ln_w, ln_b, out);
}

// Round 4
// 180.050 us; speedup vs baseline: 1.5636x; 1.1060x over previous
//
#include <hip/hip_runtime.h>
#include <hip/hip_bf16.h>
#include <math.h>

#define PI_F 3.14159265358979f

typedef __attribute__((ext_vector_type(8))) short bf16x8;   // 8 bf16 (4 VGPRs)
typedef __attribute__((ext_vector_type(4))) float f32x4;

#define DM 512
#define LSEQ 2048
#define NB 8
#define NFFT 4096
#define MTOK (NB*LSEQ)

__device__ __forceinline__ float frcp(float x) { return __builtin_amdgcn_rcpf(x); }

// Padded LDS index: +1 word per 32 -> stride-512 reads stay 2-way (free).
__device__ __forceinline__ int PD(int i) { return i + (i >> 5); }
#define LDSN 4224   // PD(4095)=4222

// ---------------- 8-point DFT in registers ----------------
template<bool INV>
__device__ __forceinline__ void dft8(const float xr[8], const float xi[8],
                                     float yr[8], float yi[8]) {
  const float C = 0.70710678118654752f;
  float t0r=xr[0]+xr[4], t0i=xi[0]+xi[4];
  float t1r=xr[0]-xr[4], t1i=xi[0]-xi[4];
  float t2r=xr[2]+xr[6], t2i=xi[2]+xi[6];
  float t3r=xr[2]-xr[6], t3i=xi[2]-xi[6];
  float it3r = INV ? -t3i : t3i;
  float it3i = INV ?  t3r : -t3r;
  float E0r=t0r+t2r, E0i=t0i+t2i;
  float E2r=t0r-t2r, E2i=t0i-t2i;
  float E1r=t1r+it3r, E1i=t1i+it3i;
  float E3r=t1r-it3r, E3i=t1i-it3i;
  float u0r=xr[1]+xr[5], u0i=xi[1]+xi[5];
  float u1r=xr[1]-xr[5], u1i=xi[1]-xi[5];
  float u2r=xr[3]+xr[7], u2i=xi[3]+xi[7];
  float u3r=xr[3]-xr[7], u3i=xi[3]-xi[7];
  float iu3r = INV ? -u3i : u3i;
  float iu3i = INV ?  u3r : -u3r;
  float O0r=u0r+u2r, O0i=u0i+u2i;
  float O2r=u0r-u2r, O2i=u0i-u2i;
  float O1r=u1r+iu3r, O1i=u1i+iu3i;
  float O3r=u1r-iu3r, O3i=u1i-iu3i;
  float w1r = INV ? C*(O1r-O1i) : C*(O1r+O1i);
  float w1i = INV ? C*(O1r+O1i) : C*(O1i-O1r);
  float w2r = INV ? -O2i : O2i;
  float w2i = INV ?  O2r : -O2r;
  float w3r = INV ? -C*(O3r+O3i) : C*(O3i-O3r);
  float w3i = INV ?  C*(O3r-O3i) : -C*(O3r+O3i);
  yr[0]=E0r+O0r; yi[0]=E0i+O0i;
  yr[4]=E0r-O0r; yi[4]=E0i-O0i;
  yr[1]=E1r+w1r; yi[1]=E1i+w1i;
  yr[5]=E1r-w1r; yi[5]=E1i-w1i;
  yr[2]=E2r+w2r; yi[2]=E2i+w2i;
  yr[6]=E2r-w2r; yi[6]=E2i-w2i;
  yr[3]=E3r+w3r; yi[3]=E3i+w3i;
  yr[7]=E3r-w3r; yi[7]=E3i-w3i;
}

// ---------------- Stockham radix-8 stage (register-staged, single buffer) ---
template<bool INV, int SH, int NBF>
__device__ __forceinline__ void r8_stage(float* sr, float* si, int tid,
                                         float c1, float s1f) {
  float yr[8], yi[8];
  bool act = (NBF >= 512) || (tid < NBF);
  __syncthreads();
  if (act) {
    float xr[8], xi[8];
    #pragma unroll
    for (int m = 0; m < 8; ++m) {
      int ix = PD(tid + m * NBF);
      xr[m] = sr[ix]; xi[m] = si[ix];
    }
    if (SH > 0) {
      float s1 = INV ? -s1f : s1f;
      float wr = c1, wi = s1;
      #pragma unroll
      for (int m = 1; m < 8; ++m) {
        float tr = xr[m]*wr - xi[m]*wi;
        float ti = xr[m]*wi + xi[m]*wr;
        xr[m] = tr; xi[m] = ti;
        float nr = wr*c1 - wi*s1;
        float ni = wr*s1 + wi*c1;
        wr = nr; wi = ni;
      }
    }
    dft8<INV>(xr, xi, yr, yi);
  }
  __syncthreads();
  if (act) {
    int r = tid & ((1 << SH) - 1);
    int q = tid >> SH;
    int base = (q << (SH + 3)) + r;
    #pragma unroll
    for (int p = 0; p < 8; ++p) {
      int ix = PD(base + p * (1 << SH));
      sr[ix] = yr[p]; si[ix] = yi[p];
    }
  }
}

// ---------------- Stockham radix-4 stage (final stage for N=2048) ----------
template<bool INV, int SH, int NBF>
__device__ __forceinline__ void r4_stage(float* sr, float* si, int tid,
                                         float c1, float s1f) {
  float yr[4], yi[4];
  bool act = (NBF >= 512) || (tid < NBF);
  __syncthreads();
  if (act) {
    float xr[4], xi[4];
    #pragma unroll
    for (int m = 0; m < 4; ++m) {
      int ix = PD(tid + m * NBF);
      xr[m] = sr[ix]; xi[m] = si[ix];
    }
    if (SH > 0) {
      float s1 = INV ? -s1f : s1f;
      float wr = c1, wi = s1;
      #pragma unroll
      for (int m = 1; m < 4; ++m) {
        float tr = xr[m]*wr - xi[m]*wi;
        float ti = xr[m]*wi + xi[m]*wr;
        xr[m] = tr; xi[m] = ti;
        float nr = wr*c1 - wi*s1;
        float ni = wr*s1 + wi*c1;
        wr = nr; wi = ni;
      }
    }
    float t0r=xr[0]+xr[2], t0i=xi[0]+xi[2];
    float t1r=xr[0]-xr[2], t1i=xi[0]-xi[2];
    float t2r=xr[1]+xr[3], t2i=xi[1]+xi[3];
    float t3r=xr[1]-xr[3], t3i=xi[1]-xi[3];
    float it3r = INV ? -t3i : t3i;
    float it3i = INV ?  t3r : -t3r;
    yr[0]=t0r+t2r; yi[0]=t0i+t2i;
    yr[2]=t0r-t2r; yi[2]=t0i-t2i;
    yr[1]=t1r+it3r; yi[1]=t1i+it3i;
    yr[3]=t1r-it3r; yi[3]=t1i-it3i;
  }
  __syncthreads();
  if (act) {
    int r = tid & ((1 << SH) - 1);
    int q = tid >> SH;
    int base = (q << (SH + 2)) + r;
    #pragma unroll
    for (int p = 0; p < 4; ++p) {
      int ix = PD(base + p * (1 << SH));
      sr[ix] = yr[p]; si[ix] = yi[p];
    }
  }
}

// 4096 = 8*8*8*8
template<bool INV>
__device__ __forceinline__ void fft4096(float* sr, float* si, int tid,
                                        float c3, float s3, float c6, float s6,
                                        float c9, float s9) {
  r8_stage<INV, 0, 512>(sr, si, tid, 1.f, 0.f);
  r8_stage<INV, 3, 512>(sr, si, tid, c3, s3);
  r8_stage<INV, 6, 512>(sr, si, tid, c6, s6);
  r8_stage<INV, 9, 512>(sr, si, tid, c9, s9);
  __syncthreads();
}

// 2048 = 8*8*8*4
template<bool INV>
__device__ __forceinline__ void fft2048(float* sr, float* si, int tid,
                                        float c3, float s3, float c6, float s6,
                                        float c9, float s9) {
  r8_stage<INV, 0, 256>(sr, si, tid, 1.f, 0.f);
  r8_stage<INV, 3, 256>(sr, si, tid, c3, s3);
  r8_stage<INV, 6, 256>(sr, si, tid, c6, s6);
  r4_stage<INV, 9, 512>(sr, si, tid, c9, s9);
  __syncthreads();
}

// ---------------- Kernel 0: precompute per-(h,n) Cauchy coefficients --------
// struct of 12 floats: w00r w00i w01r w01i w10r w10i w11 lre lim pad pad pad
__global__ __launch_bounds__(256) void k_wprep(
    const float* __restrict__ lam_re, const float* __restrict__ lam_im,
    const float* __restrict__ p_re,   const float* __restrict__ p_im,
    const float* __restrict__ B_re,   const float* __restrict__ B_im,
    const float* __restrict__ Ct_re,  const float* __restrict__ Ct_im,
    float* __restrict__ wtab) {
  int idx = blockIdx.x * 256 + threadIdx.x;   // 0..32767 = h*64+n
  int n = idx & 63;
  float br = B_re[idx],  bi = B_im[idx];
  float cr = Ct_re[idx], ci = Ct_im[idx];
  float pr = p_re[n],    pi = p_im[n];
  float* w = wtab + (size_t)idx * 12;
  w[0] = cr*br + ci*bi;   w[1] = cr*bi - ci*br;
  w[2] = cr*pr + ci*pi;   w[3] = cr*pi - ci*pr;
  w[4] = pr*br + pi*bi;   w[5] = pr*bi - pi*br;
  w[6] = pr*pr + pi*pi;
  w[7] = lam_re[n];       w[8] = lam_im[n];
  w[9] = 0.f; w[10] = 0.f; w[11] = 0.f;
}

// ---------------- Kernel 1a: Cauchy sums -> at_roots ----------------
// grid: 512h * 4 chunks; block 512; one l per thread. No LDS.
// NOTE: omega must use PRECISE sincosf — at l=1024 (Nyquist) the reference
// relies on sin(-pi_f32) ~ -8.7e-8 != 0 to keep g finite. Hardware
// __sincosf returns exactly 0 there -> 0*inf = NaN (round-3 failure).
__global__ __launch_bounds__(512) void k_cauchy(
    const float* __restrict__ wtab, const float* __restrict__ log_step,
    float2* __restrict__ atr) {
  int h = blockIdx.x >> 2;
  int l = ((blockIdx.x & 3) << 9) + threadIdx.x;
  float two_over_step = 2.0f * expf(-log_step[h]);
  float omi, omr;
  sincosf(-2.0f * PI_F * (float)l / (float)LSEQ, &omi, &omr);
  float a = 1.0f + omr;
  float invden = frcp(a*a + omi*omi);
  float cr = 2.0f * a * invden, ci = -2.0f * omi * invden;
  float gr = two_over_step * (1.0f - omr*omr - omi*omi) * invden;
  float gi = two_over_step * (-2.0f * omi) * invden;
  float k00r=0,k00i=0,k01r=0,k01i=0,k10r=0,k10i=0,k11r=0,k11i=0;
  const float* wp = wtab + (size_t)h * 64 * 12;
  #pragma unroll 4
  for (int n = 0; n < 64; ++n) {
    float w00r = wp[n*12+0], w00i = wp[n*12+1];
    float w01r = wp[n*12+2], w01i = wp[n*12+3];
    float w10r = wp[n*12+4], w10i = wp[n*12+5];
    float w11  = wp[n*12+6];
    float dr = gr - wp[n*12+7], di = gi - wp[n*12+8];
    float inv = frcp(dr*dr + di*di);
    float car = dr * inv, cai = -di * inv;
    k00r += w00r*car - w00i*cai;  k00i += w00r*cai + w00i*car;
    k01r += w01r*car - w01i*cai;  k01i += w01r*cai + w01i*car;
    k10r += w10r*car - w10i*cai;  k10i += w10r*cai + w10i*car;
    k11r += w11*car;              k11i += w11*cai;
  }
  float tr = k01r*k10r - k01i*k10i, ti = k01r*k10i + k01i*k10r;
  float d1r = 1.0f + k11r, d1i = k11i;
  float invd1 = frcp(d1r*d1r + d1i*d1i);
  float t2r = (tr*d1r + ti*d1i) * invd1;
  float t2i = (ti*d1r - tr*d1i) * invd1;
  float numr = k00r - t2r, numi = k00i - t2i;
  atr[(size_t)h * LSEQ + l] = make_float2(cr*numr - ci*numi, cr*numi + ci*numr);
}

// ---------------- Kernel 1b: at_roots -> ifft2048 -> pad -> fft4096 -> Kf ---
__global__ __launch_bounds__(512) void k_fftK(const float2* __restrict__ atr,
                                              float2* __restrict__ Kf) {
  __shared__ float sr[LDSN], si[LDSN];
  int h = blockIdx.x, tid = threadIdx.x;
  float c3, s3, c6, s6, c9a, s9a, c9b, s9b;
  { int r = tid & 7;   sincosf(-2.f*PI_F*(float)r/64.f,   &s3,  &c3);  }
  { int r = tid & 63;  sincosf(-2.f*PI_F*(float)r/512.f,  &s6,  &c6);  }
  { int r = tid & 511; sincosf(-2.f*PI_F*(float)r/4096.f, &s9a, &c9a); }
  { int r = tid & 511; sincosf(-2.f*PI_F*(float)r/2048.f, &s9b, &c9b); }
  const float2* ap = atr + (size_t)h * LSEQ;
  #pragma unroll
  for (int i = 0; i < 4; ++i) {
    int l = tid + i*512;
    float2 v = ap[l];
    sr[PD(l)] = v.x; si[PD(l)] = v.y;
  }
  fft2048<true>(sr, si, tid, c3, s3, c6, s6, c9b, s9b);
  for (int m = tid; m < NFFT; m += 512) {
    float v = (m < LSEQ) ? sr[PD(m)] * (1.0f / (float)LSEQ) : 0.0f;
    sr[PD(m)] = v;
    si[PD(m)] = 0.0f;
  }
  fft4096<false>(sr, si, tid, c3, s3, c6, s6, c9a, s9a);
  float2* ko = Kf + (size_t)h * NFFT;
  for (int f = tid; f < NFFT; f += 512)
    ko[f] = make_float2(sr[PD(f)], si[PD(f)]);
}

// ---------------- Kernel 2: transpose u (B,L,D) -> ut (B,D,L) ----------------
__global__ __launch_bounds__(256) void k_tr_u(const float* __restrict__ u,
                                              float* __restrict__ ut) {
  __shared__ float t[32][33];
  int b = blockIdx.z;
  int l0 = blockIdx.x * 32, h0 = blockIdx.y * 32;
  int x = threadIdx.x, y0 = threadIdx.y;
  #pragma unroll
  for (int i = 0; i < 4; ++i) {
    int y = y0 + i*8;
    t[y][x] = u[((size_t)b*LSEQ + l0 + y) * DM + h0 + x];
  }
  __syncthreads();
  #pragma unroll
  for (int i = 0; i < 4; ++i) {
    int y = y0 + i*8;
    ut[((size_t)b*DM + h0 + y) * LSEQ + l0 + x] = t[x][y];
  }
}

// ---------------- Kernel 3: FFT convolution + D*u + GELU (in-place) --------
__global__ __launch_bounds__(512) void k_conv(float* __restrict__ ut,
                                              const float2* __restrict__ Kf,
                                              const float* __restrict__ Dvec) {
  __shared__ float sr[LDSN], si[LDSN];
  int wg = blockIdx.x;
  int b = wg >> 8, hp = wg & 255;
  int h0 = hp * 2, h1 = h0 + 1;
  int tid = threadIdx.x;
  float c3, s3, c6, s6, c9, s9;
  { int r = tid & 7;   sincosf(-2.f*PI_F*(float)r/64.f,   &s3, &c3); }
  { int r = tid & 63;  sincosf(-2.f*PI_F*(float)r/512.f,  &s6, &c6); }
  { int r = tid & 511; sincosf(-2.f*PI_F*(float)r/4096.f, &s9, &c9); }
  float* u0p = ut + ((size_t)(b*DM + h0)) * LSEQ;
  float* u1p = ut + ((size_t)(b*DM + h1)) * LSEQ;
  float u0reg[4], u1reg[4];
  #pragma unroll
  for (int i = 0; i < 4; ++i) {
    int l = tid + i*512;
    float a = u0p[l], c = u1p[l];
    u0reg[i] = a; u1reg[i] = c;
    sr[PD(l)] = a;  si[PD(l)] = c;
    sr[PD(l + LSEQ)] = 0.0f;  si[PD(l + LSEQ)] = 0.0f;
  }
  fft4096<false>(sr, si, tid, c3, s3, c6, s6, c9, s9);
  float yrg[8], yig[8];
  const float2* k0p = Kf + (size_t)h0 * NFFT;
  const float2* k1p = Kf + (size_t)h1 * NFFT;
  #pragma unroll
  for (int i = 0; i < 8; ++i) {
    int f = tid + i*512;
    int fn = (NFFT - f) & (NFFT - 1);
    float ar = sr[PD(f)],  ai = si[PD(f)];
    float br = sr[PD(fn)], bi = -si[PD(fn)];
    float u0r = 0.5f*(ar + br), u0i = 0.5f*(ai + bi);
    float u1r = 0.5f*(ai - bi), u1i = -0.5f*(ar - br);
    float2 K0 = k0p[f], K1 = k1p[f];
    float y0r = u0r*K0.x - u0i*K0.y, y0i = u0r*K0.y + u0i*K0.x;
    float y1r = u1r*K1.x - u1i*K1.y, y1i = u1r*K1.y + u1i*K1.x;
    yrg[i] = y0r - y1i;
    yig[i] = y0i + y1r;
  }
  __syncthreads();
  #pragma unroll
  for (int i = 0; i < 8; ++i) {
    int f = tid + i*512;
    sr[PD(f)] = yrg[i]; si[PD(f)] = yig[i];
  }
  fft4096<true>(sr, si, tid, c3, s3, c6, s6, c9, s9);
  float d0 = Dvec[h0], d1 = Dvec[h1];
  const float inv_n = 1.0f / (float)NFFT;
  #pragma unroll
  for (int i = 0; i < 4; ++i) {
    int l = tid + i*512;
    float y0 = sr[PD(l)]*inv_n + d0*u0reg[i];
    float y1 = si[PD(l)]*inv_n + d1*u1reg[i];
    u0p[l] = 0.5f*y0*(1.0f + erff(y0*0.70710678118f));
    u1p[l] = 0.5f*y1*(1.0f + erff(y1*0.70710678118f));
  }
}

// ---------------- Kernel 4: transpose z (B,D,L) f32 -> Zb (M,D) bf16 --------
__global__ __launch_bounds__(256) void k_tr_z(const float* __restrict__ zt,
                                              __hip_bfloat16* __restrict__ Zb) {
  __shared__ float t[32][33];
  int b = blockIdx.z;
  int h0 = blockIdx.x * 32, l0 = blockIdx.y * 32;
  int x = threadIdx.x, y0 = threadIdx.y;
  #pragma unroll
  for (int i = 0; i < 4; ++i) {
    int y = y0 + i*8;
    t[y][x] = zt[((size_t)b*DM + h0 + y) * LSEQ + l0 + x];
  }
  __syncthreads();
  #pragma unroll
  for (int i = 0; i < 4; ++i) {
    int y = y0 + i*8;
    Zb[((size_t)b*LSEQ + l0 + y) * DM + h0 + x] = __float2bfloat16(t[x][y]);
  }
}

// ---------------- Kernel 5: cast W to bf16 ----------------
__global__ __launch_bounds__(256) void k_cast_w(const float* __restrict__ W,
                                                __hip_bfloat16* __restrict__ Wb) {
  int i = blockIdx.x * 256 + threadIdx.x;
  Wb[i] = __float2bfloat16(W[i]);
}

// ---------------- Kernel 6: GEMM  out = Z @ W^T + b + u  (pre-LN) ----------
__global__ __launch_bounds__(256) void k_gemm(const short* __restrict__ Z,
                                              const short* __restrict__ Wb,
                                              const float* __restrict__ bias,
                                              const float* __restrict__ u,
                                              float* __restrict__ gout) {
  __shared__ short sA[64][40];
  __shared__ short sB[64][40];
  int tid = threadIdx.x;
  int wave = tid >> 6, lane = tid & 63;
  int wm = wave >> 1, wn = wave & 1;
  int m0 = blockIdx.x * 64, n0 = blockIdx.y * 64;
  int srow = tid >> 2, skb = (tid & 3) << 3;
  int row = lane & 15, kq8 = (lane >> 4) << 3;
  f32x4 acc00 = {0.f,0.f,0.f,0.f}, acc01 = {0.f,0.f,0.f,0.f};
  f32x4 acc10 = {0.f,0.f,0.f,0.f}, acc11 = {0.f,0.f,0.f,0.f};
  for (int k0 = 0; k0 < DM; k0 += 32) {
    __syncthreads();
    *(uint4*)&sA[srow][skb] = *(const uint4*)(Z  + (size_t)(m0 + srow) * DM + k0 + skb);
    *(uint4*)&sB[srow][skb] = *(const uint4*)(Wb + (size_t)(n0 + srow) * DM + k0 + skb);
    __syncthreads();
    bf16x8 a0 = *(const bf16x8*)&sA[wm*32 + row][kq8];
    bf16x8 a1 = *(const bf16x8*)&sA[wm*32 + 16 + row][kq8];
    bf16x8 b0 = *(const bf16x8*)&sB[wn*32 + row][kq8];
    bf16x8 b1 = *(const bf16x8*)&sB[wn*32 + 16 + row][kq8];
    acc00 = __builtin_amdgcn_mfma_f32_16x16x32_bf16(a0, b0, acc00, 0, 0, 0);
    acc01 = __builtin_amdgcn_mfma_f32_16x16x32_bf16(a0, b1, acc01, 0, 0, 0);
    acc10 = __builtin_amdgcn_mfma_f32_16x16x32_bf16(a1, b0, acc10, 0, 0, 0);
    acc11 = __builtin_amdgcn_mfma_f32_16x16x32_bf16(a1, b1, acc11, 0, 0, 0);
  }
  int crow = (lane >> 4) << 2, ccol = lane & 15;
  #pragma unroll
  for (int rr = 0; rr < 4; ++rr) {
    int mmA = m0 + wm*32 + crow + rr;
    int mmB = mmA + 16;
    int ooA = n0 + wn*32 + ccol;
    int ooB = ooA + 16;
    size_t iAA = (size_t)mmA * DM + ooA, iAB = (size_t)mmA * DM + ooB;
    size_t iBA = (size_t)mmB * DM + ooA, iBB = (size_t)mmB * DM + ooB;
    gout[iAA] = acc00[rr] + bias[ooA] + u[iAA];
    gout[iAB] = acc01[rr] + bias[ooB] + u[iAB];
    gout[iBA] = acc10[rr] + bias[ooA] + u[iBA];
    gout[iBB] = acc11[rr] + bias[ooB] + u[iBB];
  }
}

// ---------------- Kernel 7: LayerNorm ----------------
__global__ __launch_bounds__(512) void k_ln(const float* __restrict__ pre,
                                            const float* __restrict__ lnw,
                                            const float* __restrict__ lnb,
                                            float* __restrict__ out) {
  int wave = threadIdx.x >> 6, lane = threadIdx.x & 63;
  int m = blockIdx.x * 8 + wave;
  const float* row = pre + (size_t)m * DM;
  float v[8]; float s = 0.f, s2 = 0.f;
  #pragma unroll
  for (int i = 0; i < 8; ++i) {
    v[i] = row[lane + i*64];
    s += v[i]; s2 += v[i]*v[i];
  }
  #pragma unroll
  for (int off = 1; off < 64; off <<= 1) {
    s  += __shfl_xor(s, off);
    s2 += __shfl_xor(s2, off);
  }
  float mean = s * (1.0f/(float)DM);
  float var  = s2 * (1.0f/(float)DM) - mean*mean;
  float rstd = rsqrtf(var + 1e-5f);
  float* orow = out + (size_t)m * DM;
  #pragma unroll
  for (int i = 0; i < 8; ++i) {
    int o = lane + i*64;
    orow[o] = (v[i] - mean) * rstd * lnw[o] + lnb[o];
  }
}

// ---------------- launch ----------------
extern "C" void kernel_launch(void* const* d_in, const int* in_sizes, int n_in,
                              void* d_out, int out_size, void* d_ws, size_t ws_size,
                              hipStream_t stream) {
  const float* u        = (const float*)d_in[0];
  const float* lam_re   = (const float*)d_in[1];
  const float* lam_im   = (const float*)d_in[2];
  const float* p_re     = (const float*)d_in[3];
  const float* p_im     = (const float*)d_in[4];
  const float* B_re     = (const float*)d_in[5];
  const float* B_im     = (const float*)d_in[6];
  const float* Ct_re    = (const float*)d_in[7];
  const float* Ct_im    = (const float*)d_in[8];
  const float* log_step = (const float*)d_in[9];
  const float* Dv       = (const float*)d_in[10];
  const float* W        = (const float*)d_in[11];
  const float* bias     = (const float*)d_in[12];
  const float* ln_w     = (const float*)d_in[13];
  const float* ln_b     = (const float*)d_in[14];
  float* out = (float*)d_out;
  char* ws = (char*)d_ws;

  // ws: Kf [0,16M) | ut [16M,48M) | Zb [48M,64M) | Wb [64M,64.5M)
  // atr (8M) + wtab (1.5M) overlap the Zb region (both dead before k_tr_z).
  float2* Kf = (float2*)ws;
  float*  ut = (float*)(ws + (16u << 20));
  __hip_bfloat16* Zb = (__hip_bfloat16*)(ws + (48u << 20));
  float2* atr   = (float2*)(ws + (48u << 20));
  float*  wtab  = (float*)(ws + (56u << 20));
  __hip_bfloat16* Wb = (__hip_bfloat16*)(ws + (64u << 20));
  float* gout = ut;
  if (ws_size < (65u << 20)) return;

  k_wprep<<<dim3((DM*64)/256), dim3(256), 0, stream>>>(lam_re, lam_im, p_re, p_im,
                                                       B_re, B_im, Ct_re, Ct_im, wtab);
  k_cauchy<<<dim3(DM*4), dim3(512), 0, stream>>>(wtab, log_step, atr);
  k_fftK<<<dim3(DM), dim3(512), 0, stream>>>(atr, Kf);
  k_tr_u<<<dim3(LSEQ/32, DM/32, NB), dim3(32, 8), 0, stream>>>(u, ut);
  k_conv<<<dim3(NB * (DM/2)), dim3(512), 0, stream>>>(ut, Kf, Dv);
  k_tr_z<<<dim3(DM/32, LSEQ/32, NB), dim3(32, 8), 0, stream>>>(ut, Zb);
  k_cast_w<<<dim3((DM*DM)/256), dim3(256), 0, stream>>>(W, Wb);
  k_gemm<<<dim3(MTOK/64, DM/64), dim3(256), 0, stream>>>((const short*)Zb, (const short*)Wb,
                                                         bias, u, gout);
  k_ln<<<dim3(MTOK/8), dim3(512), 0, stream>>>(gout, ln_w, ln_b, out);
}

// Round 5
// 172.874 us; speedup vs baseline: 1.6285x; 1.0415x over previous
//
#include <hip/hip_runtime.h>
#include <hip/hip_bf16.h>
#include <math.h>

#define PI_F 3.14159265358979f

typedef __attribute__((ext_vector_type(8))) short bf16x8;   // 8 bf16 (4 VGPRs)
typedef __attribute__((ext_vector_type(4))) float f32x4;

#define DM 512
#define LSEQ 2048
#define NB 8
#define NFFT 4096
#define MTOK (NB*LSEQ)

__device__ __forceinline__ float frcp(float x) { return __builtin_amdgcn_rcpf(x); }

// Padded complex-LDS index: +1 float2 per 16 (8B pad per 128B).
__device__ __forceinline__ int PC(int i) { return i + (i >> 4); }
#define LDSC 4352   // PC(4095)=4350

// ---------------- 8-point DFT in registers ----------------
template<bool INV>
__device__ __forceinline__ void dft8(const float xr[8], const float xi[8],
                                     float yr[8], float yi[8]) {
  const float C = 0.70710678118654752f;
  float t0r=xr[0]+xr[4], t0i=xi[0]+xi[4];
  float t1r=xr[0]-xr[4], t1i=xi[0]-xi[4];
  float t2r=xr[2]+xr[6], t2i=xi[2]+xi[6];
  float t3r=xr[2]-xr[6], t3i=xi[2]-xi[6];
  float it3r = INV ? -t3i : t3i;
  float it3i = INV ?  t3r : -t3r;
  float E0r=t0r+t2r, E0i=t0i+t2i;
  float E2r=t0r-t2r, E2i=t0i-t2i;
  float E1r=t1r+it3r, E1i=t1i+it3i;
  float E3r=t1r-it3r, E3i=t1i-it3i;
  float u0r=xr[1]+xr[5], u0i=xi[1]+xi[5];
  float u1r=xr[1]-xr[5], u1i=xi[1]-xi[5];
  float u2r=xr[3]+xr[7], u2i=xi[3]+xi[7];
  float u3r=xr[3]-xr[7], u3i=xi[3]-xi[7];
  float iu3r = INV ? -u3i : u3i;
  float iu3i = INV ?  u3r : -u3r;
  float O0r=u0r+u2r, O0i=u0i+u2i;
  float O2r=u0r-u2r, O2i=u0i-u2i;
  float O1r=u1r+iu3r, O1i=u1i+iu3i;
  float O3r=u1r-iu3r, O3i=u1i-iu3i;
  float w1r = INV ? C*(O1r-O1i) : C*(O1r+O1i);
  float w1i = INV ? C*(O1r+O1i) : C*(O1i-O1r);
  float w2r = INV ? -O2i : O2i;
  float w2i = INV ?  O2r : -O2r;
  float w3r = INV ? -C*(O3r+O3i) : C*(O3i-O3r);
  float w3i = INV ?  C*(O3r-O3i) : -C*(O3r+O3i);
  yr[0]=E0r+O0r; yi[0]=E0i+O0i;
  yr[4]=E0r-O0r; yi[4]=E0i-O0i;
  yr[1]=E1r+w1r; yi[1]=E1i+w1i;
  yr[5]=E1r-w1r; yi[5]=E1i-w1i;
  yr[2]=E2r+w2r; yi[2]=E2i+w2i;
  yr[6]=E2r-w2r; yi[6]=E2i-w2i;
  yr[3]=E3r+w3r; yi[3]=E3i+w3i;
  yr[7]=E3r-w3r; yi[7]=E3i-w3i;
}

// ---------------- Stockham radix-8 stage, interleaved float2 LDS ----------
template<bool INV, int SH, int NBF>
__device__ __forceinline__ void r8c(float2* sc, int tid, float c1, float s1f) {
  float yr[8], yi[8];
  bool act = (NBF >= 512) || (tid < NBF);
  __syncthreads();
  if (act) {
    float xr[8], xi[8];
    #pragma unroll
    for (int m = 0; m < 8; ++m) {
      float2 v = sc[PC(tid + m * NBF)];
      xr[m] = v.x; xi[m] = v.y;
    }
    if (SH > 0) {
      float s1 = INV ? -s1f : s1f;
      float wr = c1, wi = s1;
      #pragma unroll
      for (int m = 1; m < 8; ++m) {
        float tr = xr[m]*wr - xi[m]*wi;
        float ti = xr[m]*wi + xi[m]*wr;
        xr[m] = tr; xi[m] = ti;
        float nr = wr*c1 - wi*s1;
        float ni = wr*s1 + wi*c1;
        wr = nr; wi = ni;
      }
    }
    dft8<INV>(xr, xi, yr, yi);
  }
  __syncthreads();
  if (act) {
    int r = tid & ((1 << SH) - 1);
    int q = tid >> SH;
    int base = (q << (SH + 3)) + r;
    #pragma unroll
    for (int p = 0; p < 8; ++p)
      sc[PC(base + (p << SH))] = make_float2(yr[p], yi[p]);
  }
}

// ---------------- Stockham radix-4 stage (final for N=2048) ----------------
template<bool INV, int SH, int NBF>
__device__ __forceinline__ void r4c(float2* sc, int tid, float c1, float s1f) {
  float yr[4], yi[4];
  bool act = (NBF >= 512) || (tid < NBF);
  __syncthreads();
  if (act) {
    float xr[4], xi[4];
    #pragma unroll
    for (int m = 0; m < 4; ++m) {
      float2 v = sc[PC(tid + m * NBF)];
      xr[m] = v.x; xi[m] = v.y;
    }
    if (SH > 0) {
      float s1 = INV ? -s1f : s1f;
      float wr = c1, wi = s1;
      #pragma unroll
      for (int m = 1; m < 4; ++m) {
        float tr = xr[m]*wr - xi[m]*wi;
        float ti = xr[m]*wi + xi[m]*wr;
        xr[m] = tr; xi[m] = ti;
        float nr = wr*c1 - wi*s1;
        float ni = wr*s1 + wi*c1;
        wr = nr; wi = ni;
      }
    }
    float t0r=xr[0]+xr[2], t0i=xi[0]+xi[2];
    float t1r=xr[0]-xr[2], t1i=xi[0]-xi[2];
    float t2r=xr[1]+xr[3], t2i=xi[1]+xi[3];
    float t3r=xr[1]-xr[3], t3i=xi[1]-xi[3];
    float it3r = INV ? -t3i : t3i;
    float it3i = INV ?  t3r : -t3r;
    yr[0]=t0r+t2r; yi[0]=t0i+t2i;
    yr[2]=t0r-t2r; yi[2]=t0i-t2i;
    yr[1]=t1r+it3r; yi[1]=t1i+it3i;
    yr[3]=t1r-it3r; yi[3]=t1i-it3i;
  }
  __syncthreads();
  if (act) {
    int r = tid & ((1 << SH) - 1);
    int q = tid >> SH;
    int base = (q << (SH + 2)) + r;
    #pragma unroll
    for (int p = 0; p < 4; ++p)
      sc[PC(base + (p << SH))] = make_float2(yr[p], yi[p]);
  }
}

// 4096 = 8*8*8*8
template<bool INV>
__device__ __forceinline__ void fftc4096(float2* sc, int tid,
                                         float c3, float s3, float c6, float s6,
                                         float c9, float s9) {
  r8c<INV, 0, 512>(sc, tid, 1.f, 0.f);
  r8c<INV, 3, 512>(sc, tid, c3, s3);
  r8c<INV, 6, 512>(sc, tid, c6, s6);
  r8c<INV, 9, 512>(sc, tid, c9, s9);
  __syncthreads();
}

// 2048 = 8*8*8*4
template<bool INV>
__device__ __forceinline__ void fftc2048(float2* sc, int tid,
                                         float c3, float s3, float c6, float s6,
                                         float c9, float s9) {
  r8c<INV, 0, 256>(sc, tid, 1.f, 0.f);
  r8c<INV, 3, 256>(sc, tid, c3, s3);
  r8c<INV, 6, 256>(sc, tid, c6, s6);
  r4c<INV, 9, 512>(sc, tid, c9, s9);
  __syncthreads();
}

// ---------------- Kernel 0: precompute per-(h,n) Cauchy coefficients --------
__global__ __launch_bounds__(256) void k_wprep(
    const float* __restrict__ lam_re, const float* __restrict__ lam_im,
    const float* __restrict__ p_re,   const float* __restrict__ p_im,
    const float* __restrict__ B_re,   const float* __restrict__ B_im,
    const float* __restrict__ Ct_re,  const float* __restrict__ Ct_im,
    float* __restrict__ wtab) {
  int idx = blockIdx.x * 256 + threadIdx.x;   // 0..32767 = h*64+n
  int n = idx & 63;
  float br = B_re[idx],  bi = B_im[idx];
  float cr = Ct_re[idx], ci = Ct_im[idx];
  float pr = p_re[n],    pi = p_im[n];
  float* w = wtab + (size_t)idx * 12;
  w[0] = cr*br + ci*bi;   w[1] = cr*bi - ci*br;
  w[2] = cr*pr + ci*pi;   w[3] = cr*pi - ci*pr;
  w[4] = pr*br + pi*bi;   w[5] = pr*bi - pi*br;
  w[6] = pr*pr + pi*pi;
  w[7] = lam_re[n];       w[8] = lam_im[n];
  w[9] = 0.f; w[10] = 0.f; w[11] = 0.f;
}

// ---------------- Kernel 1a: Cauchy sums -> at_roots ----------------
// PRECISE sincosf required: at l=1024 (Nyquist) reference relies on
// sin(-pi_f32) ~ -8.7e-8 != 0; hw __sincosf gives exact 0 -> NaN.
__global__ __launch_bounds__(512) void k_cauchy(
    const float* __restrict__ wtab, const float* __restrict__ log_step,
    float2* __restrict__ atr) {
  int h = blockIdx.x >> 2;
  int l = ((blockIdx.x & 3) << 9) + threadIdx.x;
  float two_over_step = 2.0f * expf(-log_step[h]);
  float omi, omr;
  sincosf(-2.0f * PI_F * (float)l / (float)LSEQ, &omi, &omr);
  float a = 1.0f + omr;
  float invden = frcp(a*a + omi*omi);
  float cr = 2.0f * a * invden, ci = -2.0f * omi * invden;
  float gr = two_over_step * (1.0f - omr*omr - omi*omi) * invden;
  float gi = two_over_step * (-2.0f * omi) * invden;
  float k00r=0,k00i=0,k01r=0,k01i=0,k10r=0,k10i=0,k11r=0,k11i=0;
  const float* wp = wtab + (size_t)h * 64 * 12;
  #pragma unroll 4
  for (int n = 0; n < 64; ++n) {
    float w00r = wp[n*12+0], w00i = wp[n*12+1];
    float w01r = wp[n*12+2], w01i = wp[n*12+3];
    float w10r = wp[n*12+4], w10i = wp[n*12+5];
    float w11  = wp[n*12+6];
    float dr = gr - wp[n*12+7], di = gi - wp[n*12+8];
    float inv = frcp(dr*dr + di*di);
    float car = dr * inv, cai = -di * inv;
    k00r += w00r*car - w00i*cai;  k00i += w00r*cai + w00i*car;
    k01r += w01r*car - w01i*cai;  k01i += w01r*cai + w01i*car;
    k10r += w10r*car - w10i*cai;  k10i += w10r*cai + w10i*car;
    k11r += w11*car;              k11i += w11*cai;
  }
  float tr = k01r*k10r - k01i*k10i, ti = k01r*k10i + k01i*k10r;
  float d1r = 1.0f + k11r, d1i = k11i;
  float invd1 = frcp(d1r*d1r + d1i*d1i);
  float t2r = (tr*d1r + ti*d1i) * invd1;
  float t2i = (ti*d1r - tr*d1i) * invd1;
  float numr = k00r - t2r, numi = k00i - t2i;
  atr[(size_t)h * LSEQ + l] = make_float2(cr*numr - ci*numi, cr*numi + ci*numr);
}

// ---------------- Kernel 1b: at_roots -> ifft2048 -> pad -> fft4096 -> Kf ---
__global__ __launch_bounds__(512) void k_fftK(const float2* __restrict__ atr,
                                              float2* __restrict__ Kf) {
  __shared__ float2 sc[LDSC];
  int h = blockIdx.x, tid = threadIdx.x;
  float c3, s3, c6, s6, c9a, s9a, c9b, s9b;
  { int r = tid & 7;   sincosf(-2.f*PI_F*(float)r/64.f,   &s3,  &c3);  }
  { int r = tid & 63;  sincosf(-2.f*PI_F*(float)r/512.f,  &s6,  &c6);  }
  { int r = tid & 511; sincosf(-2.f*PI_F*(float)r/4096.f, &s9a, &c9a); }
  { int r = tid & 511; sincosf(-2.f*PI_F*(float)r/2048.f, &s9b, &c9b); }
  const float2* ap = atr + (size_t)h * LSEQ;
  #pragma unroll
  for (int i = 0; i < 4; ++i) {
    int l = tid + i*512;
    sc[PC(l)] = ap[l];
  }
  fftc2048<true>(sc, tid, c3, s3, c6, s6, c9b, s9b);
  for (int m = tid; m < NFFT; m += 512) {
    float v = (m < LSEQ) ? sc[PC(m)].x * (1.0f / (float)LSEQ) : 0.0f;
    sc[PC(m)] = make_float2(v, 0.0f);
  }
  fftc4096<false>(sc, tid, c3, s3, c6, s6, c9a, s9a);
  float2* ko = Kf + (size_t)h * NFFT;
  for (int f = tid; f < NFFT; f += 512)
    ko[f] = sc[PC(f)];
}

// ---------------- Kernel 2: transpose u (B,L,D) f32 -> ut (B,D,L) ----------
__global__ __launch_bounds__(256) void k_tr_u(const float* __restrict__ u,
                                              float* __restrict__ ut) {
  __shared__ float t[32][33];
  int b = blockIdx.z;
  int l0 = blockIdx.x * 32, h0 = blockIdx.y * 32;
  int x = threadIdx.x, y0 = threadIdx.y;
  #pragma unroll
  for (int i = 0; i < 4; ++i) {
    int y = y0 + i*8;
    t[y][x] = u[((size_t)b*LSEQ + l0 + y) * DM + h0 + x];
  }
  __syncthreads();
  #pragma unroll
  for (int i = 0; i < 4; ++i) {
    int y = y0 + i*8;
    ut[((size_t)b*DM + h0 + y) * LSEQ + l0 + x] = t[x][y];
  }
}

// ---------------- Kernel 3: FFT conv + D*u + GELU -> zbt (bf16, B,D,L) -----
__global__ __launch_bounds__(512) void k_conv(const float* __restrict__ ut,
                                              const float2* __restrict__ Kf,
                                              const float* __restrict__ Dvec,
                                              __hip_bfloat16* __restrict__ zbt) {
  __shared__ float2 sc[LDSC];
  int wg = blockIdx.x;
  int b = wg >> 8, hp = wg & 255;
  int h0 = hp * 2, h1 = h0 + 1;
  int tid = threadIdx.x;
  float c3, s3, c6, s6, c9, s9;
  { int r = tid & 7;   sincosf(-2.f*PI_F*(float)r/64.f,   &s3, &c3); }
  { int r = tid & 63;  sincosf(-2.f*PI_F*(float)r/512.f,  &s6, &c6); }
  { int r = tid & 511; sincosf(-2.f*PI_F*(float)r/4096.f, &s9, &c9); }
  const float* u0p = ut + ((size_t)(b*DM + h0)) * LSEQ;
  const float* u1p = ut + ((size_t)(b*DM + h1)) * LSEQ;
  float u0reg[4], u1reg[4];
  #pragma unroll
  for (int i = 0; i < 4; ++i) {
    int l = tid + i*512;
    float a = u0p[l], c = u1p[l];
    u0reg[i] = a; u1reg[i] = c;
    sc[PC(l)] = make_float2(a, c);
    sc[PC(l + LSEQ)] = make_float2(0.0f, 0.0f);
  }
  fftc4096<false>(sc, tid, c3, s3, c6, s6, c9, s9);
  float yrg[8], yig[8];
  const float2* k0p = Kf + (size_t)h0 * NFFT;
  const float2* k1p = Kf + (size_t)h1 * NFFT;
  #pragma unroll
  for (int i = 0; i < 8; ++i) {
    int f = tid + i*512;
    int fn = (NFFT - f) & (NFFT - 1);
    float2 Za = sc[PC(f)], Zb = sc[PC(fn)];
    float ar = Za.x,  ai = Za.y;
    float br = Zb.x,  bi = -Zb.y;
    float u0r = 0.5f*(ar + br), u0i = 0.5f*(ai + bi);
    float u1r = 0.5f*(ai - bi), u1i = -0.5f*(ar - br);
    float2 K0 = k0p[f], K1 = k1p[f];
    float y0r = u0r*K0.x - u0i*K0.y, y0i = u0r*K0.y + u0i*K0.x;
    float y1r = u1r*K1.x - u1i*K1.y, y1i = u1r*K1.y + u1i*K1.x;
    yrg[i] = y0r - y1i;
    yig[i] = y0i + y1r;
  }
  __syncthreads();
  #pragma unroll
  for (int i = 0; i < 8; ++i) {
    int f = tid + i*512;
    sc[PC(f)] = make_float2(yrg[i], yig[i]);
  }
  fftc4096<true>(sc, tid, c3, s3, c6, s6, c9, s9);
  float d0 = Dvec[h0], d1 = Dvec[h1];
  __hip_bfloat16* zb0 = zbt + ((size_t)(b*DM + h0)) * LSEQ;
  __hip_bfloat16* zb1 = zbt + ((size_t)(b*DM + h1)) * LSEQ;
  const float inv_n = 1.0f / (float)NFFT;
  #pragma unroll
  for (int i = 0; i < 4; ++i) {
    int l = tid + i*512;
    float2 v = sc[PC(l)];
    float y0 = v.x*inv_n + d0*u0reg[i];
    float y1 = v.y*inv_n + d1*u1reg[i];
    float g0 = 0.5f*y0*(1.0f + erff(y0*0.70710678118f));
    float g1 = 0.5f*y1*(1.0f + erff(y1*0.70710678118f));
    zb0[l] = __float2bfloat16(g0);
    zb1[l] = __float2bfloat16(g1);
  }
}

// ---------------- Kernel 4: transpose zbt (B,D,L) bf16 -> Zb (M,D) bf16 ----
// 64x64 tiles, uint (2x bf16) loads and stores both directions.
__global__ __launch_bounds__(256) void k_tr_z(const ushort* __restrict__ zt,
                                              ushort* __restrict__ Zb) {
  __shared__ ushort t[64][74];
  int b = blockIdx.z;
  int h0 = blockIdx.x * 64, l0 = blockIdx.y * 64;
  int x = threadIdx.x;   // 0..31
  int y = threadIdx.y;   // 0..7
  #pragma unroll
  for (int j = 0; j < 8; ++j) {
    int hh = y + j*8;
    uint v = *(const uint*)(zt + ((size_t)(b*DM + h0 + hh))*LSEQ + l0 + 2*x);
    *(uint*)&t[hh][2*x] = v;
  }
  __syncthreads();
  #pragma unroll
  for (int j = 0; j < 8; ++j) {
    int ll = y + j*8;
    uint lo = t[2*x][ll];
    uint hi = t[2*x+1][ll];
    uint v = lo | (hi << 16);
    *(uint*)(Zb + ((size_t)(b*LSEQ + l0 + ll))*DM + h0 + 2*x) = v;
  }
}

// ---------------- Kernel 5: cast W to bf16 ----------------
__global__ __launch_bounds__(256) void k_cast_w(const float* __restrict__ W,
                                                __hip_bfloat16* __restrict__ Wb) {
  int i = blockIdx.x * 256 + threadIdx.x;
  Wb[i] = __float2bfloat16(W[i]);
}

// ---------------- Kernel 6: fused GEMM + bias + residual + LayerNorm -------
// Block: 64 tokens x full N=512, 8 waves (2M x 4N). K=512 in 16 steps.
__global__ __launch_bounds__(512) void k_gemm_ln(
    const short* __restrict__ Z,    // (M, D) bf16
    const short* __restrict__ Wb,   // (O, H) bf16
    const float* __restrict__ bias,
    const float* __restrict__ u,    // (M, D) f32
    const float* __restrict__ lnw, const float* __restrict__ lnb,
    float* __restrict__ out) {
  __shared__ short sA[64][40];
  __shared__ short sB[512][40];
  __shared__ float red[2][4][64];
  __shared__ float smu[64], srs[64];
  __shared__ float sln[2][DM];
  int tid = threadIdx.x, wave = tid >> 6, lane = tid & 63;
  int wm = wave >> 2, wn = wave & 3;          // 2 x 4
  int m0 = blockIdx.x * 64;
  int row = lane & 15, kq8 = (lane >> 4) << 3;
  sln[0][tid] = lnw[tid];
  sln[1][tid] = lnb[tid];
  f32x4 acc[2][8];
  #pragma unroll
  for (int i = 0; i < 2; ++i)
    #pragma unroll
    for (int j = 0; j < 8; ++j) acc[i][j] = (f32x4){0.f,0.f,0.f,0.f};
  for (int k0 = 0; k0 < DM; k0 += 32) {
    __syncthreads();
    if (tid < 256) {
      int srow = tid >> 2, skb = (tid & 3) << 3;
      *(uint4*)&sA[srow][skb] = *(const uint4*)(Z + (size_t)(m0 + srow)*DM + k0 + skb);
    }
    {
      int c = (tid & 3) << 3, r4 = tid >> 2;
      #pragma unroll
      for (int jj = 0; jj < 4; ++jj) {
        int o = r4 + jj*128;
        *(uint4*)&sB[o][c] = *(const uint4*)(Wb + (size_t)o*DM + k0 + c);
      }
    }
    __syncthreads();
    bf16x8 a0 = *(const bf16x8*)&sA[wm*32 + row][kq8];
    bf16x8 a1 = *(const bf16x8*)&sA[wm*32 + 16 + row][kq8];
    #pragma unroll
    for (int nt = 0; nt < 8; ++nt) {
      bf16x8 bf = *(const bf16x8*)&sB[wn*128 + nt*16 + row][kq8];
      acc[0][nt] = __builtin_amdgcn_mfma_f32_16x16x32_bf16(a0, bf, acc[0][nt], 0, 0, 0);
      acc[1][nt] = __builtin_amdgcn_mfma_f32_16x16x32_bf16(a1, bf, acc[1][nt], 0, 0, 0);
    }
  }
  // epilogue: bias + residual, per-row sums, cross-wave LN reduce
  int ccol = lane & 15, crow = (lane >> 4) << 2;
  #pragma unroll
  for (int rt = 0; rt < 2; ++rt) {
    #pragma unroll
    for (int rr = 0; rr < 4; ++rr) {
      int lr = wm*32 + rt*16 + crow + rr;
      int gr = m0 + lr;
      float ls = 0.f, ls2 = 0.f;
      #pragma unroll
      for (int nt = 0; nt < 8; ++nt) {
        int col = wn*128 + nt*16 + ccol;
        float v = acc[rt][nt][rr] + bias[col] + u[(size_t)gr*DM + col];
        acc[rt][nt][rr] = v;
        ls += v; ls2 += v*v;
      }
      ls  += __shfl_xor(ls, 1);  ls2 += __shfl_xor(ls2, 1);
      ls  += __shfl_xor(ls, 2);  ls2 += __shfl_xor(ls2, 2);
      ls  += __shfl_xor(ls, 4);  ls2 += __shfl_xor(ls2, 4);
      ls  += __shfl_xor(ls, 8);  ls2 += __shfl_xor(ls2, 8);
      if (ccol == 0) { red[0][wn][lr] = ls; red[1][wn][lr] = ls2; }
    }
  }
  __syncthreads();
  if (tid < 64) {
    float s = red[0][0][tid] + red[0][1][tid] + red[0][2][tid] + red[0][3][tid];
    float q = red[1][0][tid] + red[1][1][tid] + red[1][2][tid] + red[1][3][tid];
    float mean = s * (1.0f/(float)DM);
    float var  = q * (1.0f/(float)DM) - mean*mean;
    smu[tid] = mean;
    srs[tid] = rsqrtf(var + 1e-5f);
  }
  __syncthreads();
  #pragma unroll
  for (int rt = 0; rt < 2; ++rt) {
    #pragma unroll
    for (int rr = 0; rr < 4; ++rr) {
      int lr = wm*32 + rt*16 + crow + rr;
      int gr = m0 + lr;
      float mu = smu[lr], rs = srs[lr];
      #pragma unroll
      for (int nt = 0; nt < 8; ++nt) {
        int col = wn*128 + nt*16 + ccol;
        out[(size_t)gr*DM + col] = (acc[rt][nt][rr] - mu) * rs * sln[0][col] + sln[1][col];
      }
    }
  }
}

// ---------------- launch ----------------
extern "C" void kernel_launch(void* const* d_in, const int* in_sizes, int n_in,
                              void* d_out, int out_size, void* d_ws, size_t ws_size,
                              hipStream_t stream) {
  const float* u        = (const float*)d_in[0];
  const float* lam_re   = (const float*)d_in[1];
  const float* lam_im   = (const float*)d_in[2];
  const float* p_re     = (const float*)d_in[3];
  const float* p_im     = (const float*)d_in[4];
  const float* B_re     = (const float*)d_in[5];
  const float* B_im     = (const float*)d_in[6];
  const float* Ct_re    = (const float*)d_in[7];
  const float* Ct_im    = (const float*)d_in[8];
  const float* log_step = (const float*)d_in[9];
  const float* Dv       = (const float*)d_in[10];
  const float* W        = (const float*)d_in[11];
  const float* bias     = (const float*)d_in[12];
  const float* ln_w     = (const float*)d_in[13];
  const float* ln_b     = (const float*)d_in[14];
  float* out = (float*)d_out;
  char* ws = (char*)d_ws;

  // ws: Kf [0,16M) | ut f32 [16,48M) | zbt bf16 [48,64M) | Wb [64,64.5M)
  // atr (8M) + wtab (1.5M) overlap zbt region (dead before k_conv writes it).
  // Zb bf16 (16M) overlaps ut region (ut dead after k_conv).
  float2* Kf = (float2*)ws;
  float*  ut = (float*)(ws + (16u << 20));
  __hip_bfloat16* zbt = (__hip_bfloat16*)(ws + (48u << 20));
  float2* atr  = (float2*)(ws + (48u << 20));
  float*  wtab = (float*)(ws + (56u << 20));
  __hip_bfloat16* Zb = (__hip_bfloat16*)(ws + (16u << 20));
  __hip_bfloat16* Wb = (__hip_bfloat16*)(ws + (64u << 20));
  if (ws_size < (65u << 20)) return;

  k_wprep<<<dim3((DM*64)/256), dim3(256), 0, stream>>>(lam_re, lam_im, p_re, p_im,
                                                       B_re, B_im, Ct_re, Ct_im, wtab);
  k_cauchy<<<dim3(DM*4), dim3(512), 0, stream>>>(wtab, log_step, atr);
  k_fftK<<<dim3(DM), dim3(512), 0, stream>>>(atr, Kf);
  k_tr_u<<<dim3(LSEQ/32, DM/32, NB), dim3(32, 8), 0, stream>>>(u, ut);
  k_conv<<<dim3(NB * (DM/2)), dim3(512), 0, stream>>>(ut, Kf, Dv, zbt);
  k_tr_z<<<dim3(DM/64, LSEQ/64, NB), dim3(32, 8), 0, stream>>>((const ushort*)zbt, (ushort*)Zb);
  k_cast_w<<<dim3((DM*DM)/256), dim3(256), 0, stream>>>(W, Wb);
  k_gemm_ln<<<dim3(MTOK/64), dim3(512), 0, stream>>>((const short*)Zb, (const short*)Wb,
                                                     bias, u, ln_w, ln_b, out);
}

// Round 6
// 157.442 us; speedup vs baseline: 1.7882x; 1.0980x over previous
//
#include <hip/hip_runtime.h>
#include <hip/hip_bf16.h>
#include <math.h>

#define PI_F 3.14159265358979f

typedef __attribute__((ext_vector_type(8))) short bf16x8;   // 8 bf16
typedef __attribute__((ext_vector_type(4))) float f32x4;
typedef __attribute__((ext_vector_type(2))) float f32x2;

#define DM 512
#define LSEQ 2048
#define NB 8
#define NFFT 4096
#define MTOK (NB*LSEQ)

__device__ __forceinline__ float frcp(float x) { return __builtin_amdgcn_rcpf(x); }

// Padded LDS index (split f32 arrays): +1 word per 32 -> strided stages stay <=4-way.
__device__ __forceinline__ int PD(int i) { return i + (i >> 5); }
#define LDSN 4224   // PD(4095)=4222

// ---------------- 8-point DFT in registers (proven r2-r5) ----------------
template<bool INV>
__device__ __forceinline__ void dft8(const float xr[8], const float xi[8],
                                     float yr[8], float yi[8]) {
  const float C = 0.70710678118654752f;
  float t0r=xr[0]+xr[4], t0i=xi[0]+xi[4];
  float t1r=xr[0]-xr[4], t1i=xi[0]-xi[4];
  float t2r=xr[2]+xr[6], t2i=xi[2]+xi[6];
  float t3r=xr[2]-xr[6], t3i=xi[2]-xi[6];
  float it3r = INV ? -t3i : t3i;
  float it3i = INV ?  t3r : -t3r;
  float E0r=t0r+t2r, E0i=t0i+t2i;
  float E2r=t0r-t2r, E2i=t0i-t2i;
  float E1r=t1r+it3r, E1i=t1i+it3i;
  float E3r=t1r-it3r, E3i=t1i-it3i;
  float u0r=xr[1]+xr[5], u0i=xi[1]+xi[5];
  float u1r=xr[1]-xr[5], u1i=xi[1]-xi[5];
  float u2r=xr[3]+xr[7], u2i=xi[3]+xi[7];
  float u3r=xr[3]-xr[7], u3i=xi[3]-xi[7];
  float iu3r = INV ? -u3i : u3i;
  float iu3i = INV ?  u3r : -u3r;
  float O0r=u0r+u2r, O0i=u0i+u2i;
  float O2r=u0r-u2r, O2i=u0i-u2i;
  float O1r=u1r+iu3r, O1i=u1i+iu3i;
  float O3r=u1r-iu3r, O3i=u1i-iu3i;
  float w1r = INV ? C*(O1r-O1i) : C*(O1r+O1i);
  float w1i = INV ? C*(O1r+O1i) : C*(O1i-O1r);
  float w2r = INV ? -O2i : O2i;
  float w2i = INV ?  O2r : -O2r;
  float w3r = INV ? -C*(O3r+O3i) : C*(O3i-O3r);
  float w3i = INV ?  C*(O3r-O3i) : -C*(O3r+O3i);
  yr[0]=E0r+O0r; yi[0]=E0i+O0i;
  yr[4]=E0r-O0r; yi[4]=E0i-O0i;
  yr[1]=E1r+w1r; yi[1]=E1i+w1i;
  yr[5]=E1r-w1r; yi[5]=E1i-w1i;
  yr[2]=E2r+w2r; yi[2]=E2i+w2i;
  yr[6]=E2r-w2r; yi[6]=E2i-w2i;
  yr[3]=E3r+w3r; yi[3]=E3i+w3i;
  yr[7]=E3r-w3r; yi[7]=E3i-w3i;
}

// ---------------- 16-point DFT = 2 x dft8 + combine ----------------
template<bool INV>
__device__ __forceinline__ void dft16(const float xr[16], const float xi[16],
                                      float yr[16], float yi[16]) {
  float exr[8], exi[8], oxr[8], oxi[8];
  #pragma unroll
  for (int m = 0; m < 8; ++m) {
    exr[m]=xr[2*m];   exi[m]=xi[2*m];
    oxr[m]=xr[2*m+1]; oxi[m]=xi[2*m+1];
  }
  float er[8], ei[8], orr[8], oii[8];
  dft8<INV>(exr, exi, er, ei);
  dft8<INV>(oxr, oxi, orr, oii);
  const float KC = 0.92387953251128675f;   // cos(pi/8)
  const float KS = 0.38268343236508977f;   // sin(pi/8)
  const float KH = 0.70710678118654752f;
  float tr, ti;
  // k=0: w=1
  yr[0]=er[0]+orr[0]; yi[0]=ei[0]+oii[0];
  yr[8]=er[0]-orr[0]; yi[8]=ei[0]-oii[0];
  // k=1: (KC, -+KS)
  { float a=KC, b=INV?KS:-KS;
    tr=orr[1]*a-oii[1]*b; ti=orr[1]*b+oii[1]*a;
    yr[1]=er[1]+tr; yi[1]=ei[1]+ti; yr[9]=er[1]-tr; yi[9]=ei[1]-ti; }
  // k=2: (KH, -+KH)
  { float a=KH, b=INV?KH:-KH;
    tr=orr[2]*a-oii[2]*b; ti=orr[2]*b+oii[2]*a;
    yr[2]=er[2]+tr; yi[2]=ei[2]+ti; yr[10]=er[2]-tr; yi[10]=ei[2]-ti; }
  // k=3: (KS, -+KC)
  { float a=KS, b=INV?KC:-KC;
    tr=orr[3]*a-oii[3]*b; ti=orr[3]*b+oii[3]*a;
    yr[3]=er[3]+tr; yi[3]=ei[3]+ti; yr[11]=er[3]-tr; yi[11]=ei[3]-ti; }
  // k=4: (0, -+1)
  { if (INV) { tr=-oii[4]; ti= orr[4]; } else { tr= oii[4]; ti=-orr[4]; }
    yr[4]=er[4]+tr; yi[4]=ei[4]+ti; yr[12]=er[4]-tr; yi[12]=ei[4]-ti; }
  // k=5: (-KS, -+KC)
  { float a=-KS, b=INV?KC:-KC;
    tr=orr[5]*a-oii[5]*b; ti=orr[5]*b+oii[5]*a;
    yr[5]=er[5]+tr; yi[5]=ei[5]+ti; yr[13]=er[5]-tr; yi[13]=ei[5]-ti; }
  // k=6: (-KH, -+KH)
  { float a=-KH, b=INV?KH:-KH;
    tr=orr[6]*a-oii[6]*b; ti=orr[6]*b+oii[6]*a;
    yr[6]=er[6]+tr; yi[6]=ei[6]+ti; yr[14]=er[6]-tr; yi[14]=ei[6]-ti; }
  // k=7: (-KC, -+KS)
  { float a=-KC, b=INV?KS:-KS;
    tr=orr[7]*a-oii[7]*b; ti=orr[7]*b+oii[7]*a;
    yr[7]=er[7]+tr; yi[7]=ei[7]+ti; yr[15]=er[7]-tr; yi[15]=ei[7]-ti; }
}

// ---------------- Stockham radix-16 stage (256-thread blocks) --------------
// Ns = 1<<NSLOG (product of prior radices), NBF = N/16 butterflies.
template<bool INV, int NSLOG, int NBF>
__device__ __forceinline__ void r16s(float* sr, float* si, int tid,
                                     float c1, float s1f) {
  float yr[16], yi[16];
  bool act = (NBF >= 256) || (tid < NBF);
  __syncthreads();
  if (act) {
    float xr[16], xi[16];
    #pragma unroll
    for (int m = 0; m < 16; ++m) {
      int ix = PD(tid + m * NBF);
      xr[m] = sr[ix]; xi[m] = si[ix];
    }
    if (NSLOG > 0) {
      float s1 = INV ? -s1f : s1f;
      float wr = c1, wi = s1;
      #pragma unroll
      for (int m = 1; m < 16; ++m) {
        float tr = xr[m]*wr - xi[m]*wi;
        float ti = xr[m]*wi + xi[m]*wr;
        xr[m] = tr; xi[m] = ti;
        float nr = wr*c1 - wi*s1;
        float ni = wr*s1 + wi*c1;
        wr = nr; wi = ni;
      }
    }
    dft16<INV>(xr, xi, yr, yi);
  }
  __syncthreads();
  if (act) {
    int r = tid & ((1 << NSLOG) - 1);
    int q = tid >> NSLOG;
    int base = (q << (NSLOG + 4)) + r;
    #pragma unroll
    for (int p = 0; p < 16; ++p) {
      int ix = PD(base + (p << NSLOG));
      sr[ix] = yr[p]; si[ix] = yi[p];
    }
  }
}

// ---------------- Stockham radix-8 stage (256-thread blocks) --------------
template<bool INV, int NSLOG, int NBF>
__device__ __forceinline__ void r8s(float* sr, float* si, int tid,
                                    float c1, float s1f) {
  float yr[8], yi[8];
  bool act = (NBF >= 256) || (tid < NBF);
  __syncthreads();
  if (act) {
    float xr[8], xi[8];
    #pragma unroll
    for (int m = 0; m < 8; ++m) {
      int ix = PD(tid + m * NBF);
      xr[m] = sr[ix]; xi[m] = si[ix];
    }
    if (NSLOG > 0) {
      float s1 = INV ? -s1f : s1f;
      float wr = c1, wi = s1;
      #pragma unroll
      for (int m = 1; m < 8; ++m) {
        float tr = xr[m]*wr - xi[m]*wi;
        float ti = xr[m]*wi + xi[m]*wr;
        xr[m] = tr; xi[m] = ti;
        float nr = wr*c1 - wi*s1;
        float ni = wr*s1 + wi*c1;
        wr = nr; wi = ni;
      }
    }
    dft8<INV>(xr, xi, yr, yi);
  }
  __syncthreads();
  if (act) {
    int r = tid & ((1 << NSLOG) - 1);
    int q = tid >> NSLOG;
    int base = (q << (NSLOG + 3)) + r;
    #pragma unroll
    for (int p = 0; p < 8; ++p) {
      int ix = PD(base + (p << NSLOG));
      sr[ix] = yr[p]; si[ix] = yi[p];
    }
  }
}

// 4096 = 16*16*16, 256 threads
template<bool INV>
__device__ __forceinline__ void fft4096(float* sr, float* si, int tid,
                                        float cA, float sA, float cB, float sB) {
  r16s<INV, 0, 256>(sr, si, tid, 1.f, 0.f);
  r16s<INV, 4, 256>(sr, si, tid, cA, sA);   // r=tid&15, w_256
  r16s<INV, 8, 256>(sr, si, tid, cB, sB);   // r=tid,    w_4096
  __syncthreads();
}

// 2048 = 8*16*16, 256 threads (stages 1-2 half-active)
template<bool INV>
__device__ __forceinline__ void fft2048(float* sr, float* si, int tid,
                                        float cA, float sA, float cB, float sB) {
  r8s <INV, 0, 256>(sr, si, tid, 1.f, 0.f);
  r16s<INV, 3, 128>(sr, si, tid, cA, sA);   // r=tid&7,   w_128
  r16s<INV, 7, 128>(sr, si, tid, cB, sB);   // r=tid&127, w_2048
  __syncthreads();
}

// ---------------- Kernel 0: Cauchy coefficients, paired-n SoA --------------
// per (h, np): 20 floats = 9 fields x {even,odd} + 2 pad
__global__ __launch_bounds__(256) void k_wprep(
    const float* __restrict__ lam_re, const float* __restrict__ lam_im,
    const float* __restrict__ p_re,   const float* __restrict__ p_im,
    const float* __restrict__ B_re,   const float* __restrict__ B_im,
    const float* __restrict__ Ct_re,  const float* __restrict__ Ct_im,
    float* __restrict__ wtab) {
  int idx = blockIdx.x * 256 + threadIdx.x;   // h*64+n
  int h = idx >> 6, n = idx & 63;
  float br = B_re[idx],  bi = B_im[idx];
  float cr = Ct_re[idx], ci = Ct_im[idx];
  float pr = p_re[n],    pi = p_im[n];
  float* w = wtab + ((size_t)(h*32 + (n>>1))) * 20 + (n & 1);
  w[0]  = cr*br + ci*bi;   w[2]  = cr*bi - ci*br;
  w[4]  = cr*pr + ci*pi;   w[6]  = cr*pi - ci*pr;
  w[8]  = pr*br + pi*bi;   w[10] = pr*bi - pi*br;
  w[12] = pr*pr + pi*pi;
  w[14] = lam_re[n];       w[16] = lam_im[n];
}

// ---------------- Kernel 1a: Cauchy sums -> at_roots (f32x2 packed) -------
// PRECISE sincosf required at Nyquist (l=1024): hw __sincosf -> exact 0 -> NaN.
__global__ __launch_bounds__(512) void k_cauchy(
    const float* __restrict__ wtab, const float* __restrict__ log_step,
    float2* __restrict__ atr) {
  int h = blockIdx.x >> 2;
  int l = ((blockIdx.x & 3) << 9) + threadIdx.x;
  float two_over_step = 2.0f * expf(-log_step[h]);
  float omi, omr;
  sincosf(-2.0f * PI_F * (float)l / (float)LSEQ, &omi, &omr);
  float a = 1.0f + omr;
  float invden = frcp(a*a + omi*omi);
  float cr = 2.0f * a * invden, ci = -2.0f * omi * invden;
  float gr = two_over_step * (1.0f - omr*omr - omi*omi) * invden;
  float gi = two_over_step * (-2.0f * omi) * invden;
  f32x2 K00r={0.f,0.f},K00i={0.f,0.f},K01r={0.f,0.f},K01i={0.f,0.f},
        K10r={0.f,0.f},K10i={0.f,0.f},K11r={0.f,0.f},K11i={0.f,0.f};
  const f32x2* wp = (const f32x2*)(wtab + (size_t)h * 32 * 20);
  #pragma unroll 4
  for (int np = 0; np < 32; ++np) {
    f32x2 w00r = wp[np*10+0], w00i = wp[np*10+1];
    f32x2 w01r = wp[np*10+2], w01i = wp[np*10+3];
    f32x2 w10r = wp[np*10+4], w10i = wp[np*10+5];
    f32x2 w11  = wp[np*10+6];
    f32x2 dr = gr - wp[np*10+7];
    f32x2 di = gi - wp[np*10+8];
    f32x2 den = dr*dr + di*di;
    f32x2 inv; inv.x = frcp(den.x); inv.y = frcp(den.y);
    f32x2 car = dr * inv, cai = -di * inv;
    K00r += w00r*car - w00i*cai;  K00i += w00r*cai + w00i*car;
    K01r += w01r*car - w01i*cai;  K01i += w01r*cai + w01i*car;
    K10r += w10r*car - w10i*cai;  K10i += w10r*cai + w10i*car;
    K11r += w11*car;              K11i += w11*cai;
  }
  float k00r=K00r.x+K00r.y, k00i=K00i.x+K00i.y;
  float k01r=K01r.x+K01r.y, k01i=K01i.x+K01i.y;
  float k10r=K10r.x+K10r.y, k10i=K10i.x+K10i.y;
  float k11r=K11r.x+K11r.y, k11i=K11i.x+K11i.y;
  float tr = k01r*k10r - k01i*k10i, ti = k01r*k10i + k01i*k10r;
  float d1r = 1.0f + k11r, d1i = k11i;
  float invd1 = frcp(d1r*d1r + d1i*d1i);
  float t2r = (tr*d1r + ti*d1i) * invd1;
  float t2i = (ti*d1r - tr*d1i) * invd1;
  float numr = k00r - t2r, numi = k00i - t2i;
  atr[(size_t)h * LSEQ + l] = make_float2(cr*numr - ci*numi, cr*numi + ci*numr);
}

// ---------------- Kernel 1b: ifft2048 -> pad -> fft4096 -> Kf --------------
__global__ __launch_bounds__(256, 4) void k_fftK(const float2* __restrict__ atr,
                                                 float2* __restrict__ Kf) {
  __shared__ float sr[LDSN], si[LDSN];
  int h = blockIdx.x, tid = threadIdx.x;
  float c2a, s2a, c2b, s2b, c4a, s4a, c4b, s4b;
  { int r = tid & 7;   sincosf(-2.f*PI_F*(float)r/128.f,  &s2a, &c2a); }
  { int r = tid & 127; sincosf(-2.f*PI_F*(float)r/2048.f, &s2b, &c2b); }
  { int r = tid & 15;  sincosf(-2.f*PI_F*(float)r/256.f,  &s4a, &c4a); }
  { int r = tid;       sincosf(-2.f*PI_F*(float)r/4096.f, &s4b, &c4b); }
  const float2* ap = atr + (size_t)h * LSEQ;
  #pragma unroll
  for (int i = 0; i < 8; ++i) {
    int l = tid + i*256;
    float2 v = ap[l];
    sr[PD(l)] = v.x; si[PD(l)] = v.y;
  }
  fft2048<true>(sr, si, tid, c2a, s2a, c2b, s2b);
  #pragma unroll
  for (int i = 0; i < 16; ++i) {
    int m = tid + i*256;
    float v = (m < LSEQ) ? sr[PD(m)] * (1.0f / (float)LSEQ) : 0.0f;
    sr[PD(m)] = v;
    si[PD(m)] = 0.0f;
  }
  fft4096<false>(sr, si, tid, c4a, s4a, c4b, s4b);
  float2* ko = Kf + (size_t)h * NFFT;
  #pragma unroll
  for (int i = 0; i < 16; ++i) {
    int f = tid + i*256;
    ko[f] = make_float2(sr[PD(f)], si[PD(f)]);
  }
}

// ---------------- Kernel 2: transpose u (B,L,D) f32 -> ut (B,D,L) ----------
__global__ __launch_bounds__(256) void k_tr_u(const float* __restrict__ u,
                                              float* __restrict__ ut) {
  __shared__ float t[32][33];
  int b = blockIdx.z;
  int l0 = blockIdx.x * 32, h0 = blockIdx.y * 32;
  int x = threadIdx.x, y0 = threadIdx.y;
  #pragma unroll
  for (int i = 0; i < 4; ++i) {
    int y = y0 + i*8;
    t[y][x] = u[((size_t)b*LSEQ + l0 + y) * DM + h0 + x];
  }
  __syncthreads();
  #pragma unroll
  for (int i = 0; i < 4; ++i) {
    int y = y0 + i*8;
    ut[((size_t)b*DM + h0 + y) * LSEQ + l0 + x] = t[x][y];
  }
}

// ---------------- Kernel 3: FFT conv + D*u + GELU -> zbt (bf16) -----------
__global__ __launch_bounds__(256, 4) void k_conv(const float* __restrict__ ut,
                                                 const float2* __restrict__ Kf,
                                                 const float* __restrict__ Dvec,
                                                 __hip_bfloat16* __restrict__ zbt) {
  __shared__ float sr[LDSN], si[LDSN];
  int wg = blockIdx.x;
  int b = wg >> 8, hp = wg & 255;
  int h0 = hp * 2, h1 = h0 + 1;
  int tid = threadIdx.x;
  float c4a, s4a, c4b, s4b;
  { int r = tid & 15; sincosf(-2.f*PI_F*(float)r/256.f,  &s4a, &c4a); }
  { int r = tid;      sincosf(-2.f*PI_F*(float)r/4096.f, &s4b, &c4b); }
  const float* u0p = ut + ((size_t)(b*DM + h0)) * LSEQ;
  const float* u1p = ut + ((size_t)(b*DM + h1)) * LSEQ;
  #pragma unroll
  for (int i = 0; i < 8; ++i) {
    int l = tid + i*256;
    sr[PD(l)] = u0p[l];  si[PD(l)] = u1p[l];
    sr[PD(l + LSEQ)] = 0.0f;  si[PD(l + LSEQ)] = 0.0f;
  }
  fft4096<false>(sr, si, tid, c4a, s4a, c4b, s4b);
  float yrg[16], yig[16];
  const float2* k0p = Kf + (size_t)h0 * NFFT;
  const float2* k1p = Kf + (size_t)h1 * NFFT;
  #pragma unroll
  for (int i = 0; i < 16; ++i) {
    int f = tid + i*256;
    int fn = (NFFT - f) & (NFFT - 1);
    float ar = sr[PD(f)],  ai = si[PD(f)];
    float br = sr[PD(fn)], bi = -si[PD(fn)];
    float u0r = 0.5f*(ar + br), u0i = 0.5f*(ai + bi);
    float u1r = 0.5f*(ai - bi), u1i = -0.5f*(ar - br);
    float2 K0 = k0p[f], K1 = k1p[f];
    float y0r = u0r*K0.x - u0i*K0.y, y0i = u0r*K0.y + u0i*K0.x;
    float y1r = u1r*K1.x - u1i*K1.y, y1i = u1r*K1.y + u1i*K1.x;
    yrg[i] = y0r - y1i;
    yig[i] = y0i + y1r;
  }
  __syncthreads();
  #pragma unroll
  for (int i = 0; i < 16; ++i) {
    int f = tid + i*256;
    sr[PD(f)] = yrg[i]; si[PD(f)] = yig[i];
  }
  fft4096<true>(sr, si, tid, c4a, s4a, c4b, s4b);
  float d0 = Dvec[h0], d1 = Dvec[h1];
  __hip_bfloat16* zb0 = zbt + ((size_t)(b*DM + h0)) * LSEQ;
  __hip_bfloat16* zb1 = zbt + ((size_t)(b*DM + h1)) * LSEQ;
  const float inv_n = 1.0f / (float)NFFT;
  #pragma unroll
  for (int i = 0; i < 8; ++i) {
    int l = tid + i*256;
    float y0 = sr[PD(l)]*inv_n + d0*u0p[l];
    float y1 = si[PD(l)]*inv_n + d1*u1p[l];
    float g0 = 0.5f*y0*(1.0f + erff(y0*0.70710678118f));
    float g1 = 0.5f*y1*(1.0f + erff(y1*0.70710678118f));
    zb0[l] = __float2bfloat16(g0);
    zb1[l] = __float2bfloat16(g1);
  }
}

// ---------------- Kernel 4: transpose zbt (B,D,L) bf16 -> Zb (M,D) bf16 ----
__global__ __launch_bounds__(256) void k_tr_z(const ushort* __restrict__ zt,
                                              ushort* __restrict__ Zb) {
  __shared__ ushort t[64][74];
  int b = blockIdx.z;
  int h0 = blockIdx.x * 64, l0 = blockIdx.y * 64;
  int x = threadIdx.x;   // 0..31
  int y = threadIdx.y;   // 0..7
  #pragma unroll
  for (int j = 0; j < 8; ++j) {
    int hh = y + j*8;
    uint v = *(const uint*)(zt + ((size_t)(b*DM + h0 + hh))*LSEQ + l0 + 2*x);
    *(uint*)&t[hh][2*x] = v;
  }
  __syncthreads();
  #pragma unroll
  for (int j = 0; j < 8; ++j) {
    int ll = y + j*8;
    uint lo = t[2*x][ll];
    uint hi = t[2*x+1][ll];
    uint v = lo | (hi << 16);
    *(uint*)(Zb + ((size_t)(b*LSEQ + l0 + ll))*DM + h0 + 2*x) = v;
  }
}

// ---------------- Kernel 5: cast W to bf16 ----------------
__global__ __launch_bounds__(256) void k_cast_w(const float* __restrict__ W,
                                                __hip_bfloat16* __restrict__ Wb) {
  int i = blockIdx.x * 256 + threadIdx.x;
  Wb[i] = __float2bfloat16(W[i]);
}

// ---------------- Kernel 6: fused GEMM + bias + residual + LayerNorm -------
// Block: 32 tokens x full N=512, 8 waves (2M x 4N). grid 512 -> 2 blocks/CU.
__global__ __launch_bounds__(512) void k_gemm_ln(
    const short* __restrict__ Z,    // (M, D) bf16
    const short* __restrict__ Wb,   // (O, H) bf16
    const float* __restrict__ bias,
    const float* __restrict__ u,    // (M, D) f32
    const float* __restrict__ lnw, const float* __restrict__ lnb,
    float* __restrict__ out) {
  __shared__ short sA[32][40];
  __shared__ short sB[512][40];
  __shared__ float red[2][4][32];
  __shared__ float smu[32], srs[32];
  __shared__ float sln[2][DM];
  int tid = threadIdx.x, wave = tid >> 6, lane = tid & 63;
  int wm = wave >> 2, wn = wave & 3;          // 2 x 4
  int m0 = blockIdx.x * 32;
  int row = lane & 15, kq8 = (lane >> 4) << 3;
  sln[0][tid] = lnw[tid];
  sln[1][tid] = lnb[tid];
  f32x4 acc[8];
  #pragma unroll
  for (int j = 0; j < 8; ++j) acc[j] = (f32x4){0.f,0.f,0.f,0.f};
  for (int k0 = 0; k0 < DM; k0 += 32) {
    __syncthreads();
    if (tid < 128) {
      int srow = tid >> 2, skb = (tid & 3) << 3;
      *(uint4*)&sA[srow][skb] = *(const uint4*)(Z + (size_t)(m0 + srow)*DM + k0 + skb);
    }
    {
      int c = (tid & 3) << 3, r4 = tid >> 2;
      #pragma unroll
      for (int jj = 0; jj < 4; ++jj) {
        int o = r4 + jj*128;
        *(uint4*)&sB[o][c] = *(const uint4*)(Wb + (size_t)o*DM + k0 + c);
      }
    }
    __syncthreads();
    bf16x8 a0 = *(const bf16x8*)&sA[wm*16 + row][kq8];
    #pragma unroll
    for (int nt = 0; nt < 8; ++nt) {
      bf16x8 bf = *(const bf16x8*)&sB[wn*128 + nt*16 + row][kq8];
      acc[nt] = __builtin_amdgcn_mfma_f32_16x16x32_bf16(a0, bf, acc[nt], 0, 0, 0);
    }
  }
  // epilogue: bias + residual, per-row sums, cross-wave LN reduce
  int ccol = lane & 15, crow = (lane >> 4) << 2;
  #pragma unroll
  for (int rr = 0; rr < 4; ++rr) {
    int lr = wm*16 + crow + rr;
    int gr = m0 + lr;
    float ls = 0.f, ls2 = 0.f;
    #pragma unroll
    for (int nt = 0; nt < 8; ++nt) {
      int col = wn*128 + nt*16 + ccol;
      float v = acc[nt][rr] + bias[col] + u[(size_t)gr*DM + col];
      acc[nt][rr] = v;
      ls += v; ls2 += v*v;
    }
    ls  += __shfl_xor(ls, 1);  ls2 += __shfl_xor(ls2, 1);
    ls  += __shfl_xor(ls, 2);  ls2 += __shfl_xor(ls2, 2);
    ls  += __shfl_xor(ls, 4);  ls2 += __shfl_xor(ls2, 4);
    ls  += __shfl_xor(ls, 8);  ls2 += __shfl_xor(ls2, 8);
    if (ccol == 0) { red[0][wn][lr] = ls; red[1][wn][lr] = ls2; }
  }
  __syncthreads();
  if (tid < 32) {
    float s = red[0][0][tid] + red[0][1][tid] + red[0][2][tid] + red[0][3][tid];
    float q = red[1][0][tid] + red[1][1][tid] + red[1][2][tid] + red[1][3][tid];
    float mean = s * (1.0f/(float)DM);
    float var  = q * (1.0f/(float)DM) - mean*mean;
    smu[tid] = mean;
    srs[tid] = rsqrtf(var + 1e-5f);
  }
  __syncthreads();
  #pragma unroll
  for (int rr = 0; rr < 4; ++rr) {
    int lr = wm*16 + crow + rr;
    int gr = m0 + lr;
    float mu = smu[lr], rs = srs[lr];
    #pragma unroll
    for (int nt = 0; nt < 8; ++nt) {
      int col = wn*128 + nt*16 + ccol;
      out[(size_t)gr*DM + col] = (acc[nt][rr] - mu) * rs * sln[0][col] + sln[1][col];
    }
  }
}

// ---------------- launch ----------------
extern "C" void kernel_launch(void* const* d_in, const int* in_sizes, int n_in,
                              void* d_out, int out_size, void* d_ws, size_t ws_size,
                              hipStream_t stream) {
  const float* u        = (const float*)d_in[0];
  const float* lam_re   = (const float*)d_in[1];
  const float* lam_im   = (const float*)d_in[2];
  const float* p_re     = (const float*)d_in[3];
  const float* p_im     = (const float*)d_in[4];
  const float* B_re     = (const float*)d_in[5];
  const float* B_im     = (const float*)d_in[6];
  const float* Ct_re    = (const float*)d_in[7];
  const float* Ct_im    = (const float*)d_in[8];
  const float* log_step = (const float*)d_in[9];
  const float* Dv       = (const float*)d_in[10];
  const float* W        = (const float*)d_in[11];
  const float* bias     = (const float*)d_in[12];
  const float* ln_w     = (const float*)d_in[13];
  const float* ln_b     = (const float*)d_in[14];
  float* out = (float*)d_out;
  char* ws = (char*)d_ws;

  // ws: Kf [0,16M) | ut f32 [16,48M) | zbt bf16 [48,64M) | Wb [64,64.5M)
  // atr (8M) + wtab (1.3M) overlap zbt region (dead before k_conv writes it).
  // Zb bf16 (16M) overlaps ut region? NO -- ut re-read inside k_conv epilogue,
  // but k_tr_z runs after k_conv, so Zb may reuse [16,32M) safely.
  float2* Kf = (float2*)ws;
  float*  ut = (float*)(ws + (16u << 20));
  __hip_bfloat16* zbt = (__hip_bfloat16*)(ws + (48u << 20));
  float2* atr  = (float2*)(ws + (48u << 20));
  float*  wtab = (float*)(ws + (56u << 20));
  __hip_bfloat16* Zb = (__hip_bfloat16*)(ws + (16u << 20));
  __hip_bfloat16* Wb = (__hip_bfloat16*)(ws + (64u << 20));
  if (ws_size < (65u << 20)) return;

  k_wprep<<<dim3((DM*64)/256), dim3(256), 0, stream>>>(lam_re, lam_im, p_re, p_im,
                                                       B_re, B_im, Ct_re, Ct_im, wtab);
  k_cauchy<<<dim3(DM*4), dim3(512), 0, stream>>>(wtab, log_step, atr);
  k_fftK<<<dim3(DM), dim3(256), 0, stream>>>(atr, Kf);
  k_tr_u<<<dim3(LSEQ/32, DM/32, NB), dim3(32, 8), 0, stream>>>(u, ut);
  k_conv<<<dim3(NB * (DM/2)), dim3(256), 0, stream>>>(ut, Kf, Dv, zbt);
  k_tr_z<<<dim3(DM/64, LSEQ/64, NB), dim3(32, 8), 0, stream>>>((const ushort*)zbt, (ushort*)Zb);
  k_cast_w<<<dim3((DM*DM)/256), dim3(256), 0, stream>>>(W, Wb);
  k_gemm_ln<<<dim3(MTOK/32), dim3(512), 0, stream>>>((const short*)Zb, (const short*)Wb,
                                                     bias, u, ln_w, ln_b, out);
}